// Round 1
// 373.872 us; speedup vs baseline: 1.4102x; 1.4102x over previous
//
#include <hip/hip_runtime.h>

typedef __bf16 bf16_t;
typedef bf16_t bf16x8 __attribute__((ext_vector_type(8)));
typedef float f32x4 __attribute__((ext_vector_type(4)));
typedef unsigned short u16;
typedef unsigned int u32;

#define T_DIM 2048
#define N_DIM 1024
#define D_DIM 128

__device__ __forceinline__ u16 f32_to_bf16(float f) {
    u32 u = __builtin_bit_cast(u32, f);
    u += 0x7FFFu + ((u >> 16) & 1u);   // RNE
    return (u16)(u >> 16);
}
__device__ __forceinline__ float bf16_to_f32(u16 v) {
    u32 u = (u32)v << 16;
    return __builtin_bit_cast(float, u);
}

typedef __attribute__((address_space(1))) const u32 guint;
typedef __attribute__((address_space(3))) u32 luint;
// async global->LDS, 16B per lane, LDS dst = wave-uniform base + lane*16
__device__ __forceinline__ void stage16(const void* g, void* l) {
    __builtin_amdgcn_global_load_lds((guint*)g, (luint*)l, 16, 0, 0);
}

// ---- Kernel 1: RoPE + bf16 cast. 4 pairs/thread, HW sin/cos (revolutions). ----
__global__ void rope_kernel(const float* __restrict__ Q, u16* __restrict__ QR) {
    const int g = blockIdx.x * 256 + threadIdx.x;
    const int base = g * 4;
    const int t  = (base >> 9) & (T_DIM - 1);
    const int p0 = base & 511;
    const float4 qa = ((const float4*)Q)[g * 2];
    const float4 qb = ((const float4*)Q)[g * 2 + 1];
    const float vin[4][2] = {{qa.x, qa.y}, {qa.z, qa.w}, {qb.x, qb.y}, {qb.z, qb.w}};
    u16 ov[8];
    #pragma unroll
    for (int uu = 0; uu < 4; ++uu) {
        const float freq = exp2f((float)(p0 + uu) * (-1.0f / 32.0f)) * 0.15915494309189535f;
        float ph = (float)t * freq;
        ph = ph - floorf(ph);
        const float s = __builtin_amdgcn_sinf(ph);
        const float c = __builtin_amdgcn_cosf(ph);
        ov[2 * uu]     = f32_to_bf16(vin[uu][0] * c - vin[uu][1] * s);
        ov[2 * uu + 1] = f32_to_bf16(vin[uu][1] * c + vin[uu][0] * s);
    }
    ((uint4*)QR)[g] = *(const uint4*)ov;
}

// ---- Kernel 2: V -> bf16, transposed to Vt[bh][d][t] ----
__global__ void vt_kernel(const float* __restrict__ V, u16* __restrict__ Vt) {
    __shared__ u16 tile[64][65];
    const int bh   = blockIdx.x >> 6;
    const int rem  = blockIdx.x & 63;
    const int t0 = (rem >> 1) * 64, d0 = (rem & 1) * 64;
    const float* src = V + ((size_t)bh * T_DIM + t0) * D_DIM + d0;
    #pragma unroll
    for (int k = 0; k < 16; ++k) {
        int linear = k * 256 + threadIdx.x;
        int r = linear >> 6, c = linear & 63;
        tile[r][c] = f32_to_bf16(src[(size_t)r * D_DIM + c]);
    }
    __syncthreads();
    u16* dst = Vt + ((size_t)bh * D_DIM + d0) * T_DIM + t0;
    #pragma unroll
    for (int k = 0; k < 16; ++k) {
        int linear = k * 256 + threadIdx.x;
        int dr = linear >> 6, tc = linear & 63;
        dst[(size_t)dr * T_DIM + tc] = tile[tc][dr];
    }
}

// ---- Kernel 2b: QR (t,n) -> QRt (n,t) transpose, 64x64 bf16 tiles ----
__global__ void qrt_kernel(const u16* __restrict__ QR, u16* __restrict__ QRt) {
    __shared__ u16 til[64][65];
    const int bh  = blockIdx.x >> 9;
    const int rem = blockIdx.x & 511;
    const int t0 = (rem >> 4) * 64, n0 = (rem & 15) * 64;
    const u16* src = QR + (size_t)bh * ((size_t)T_DIM * N_DIM) + (size_t)t0 * N_DIM + n0;
    #pragma unroll
    for (int k = 0; k < 2; ++k) {
        int linear = k * 256 + threadIdx.x;
        int r = linear >> 3, o = linear & 7;
        uint4 v = *(const uint4*)(src + (size_t)r * N_DIM + o * 8);
        u16 tmp[8]; *(uint4*)tmp = v;
        #pragma unroll
        for (int e = 0; e < 8; ++e) til[r][o * 8 + e] = tmp[e];
    }
    __syncthreads();
    u16* dst = QRt + (size_t)bh * ((size_t)N_DIM * T_DIM) + (size_t)n0 * T_DIM + t0;
    #pragma unroll
    for (int k = 0; k < 2; ++k) {
        int linear = k * 256 + threadIdx.x;
        int nl = linear >> 3, to = linear & 7;
        u16 tmp[8];
        #pragma unroll
        for (int e = 0; e < 8; ++e) tmp[e] = til[to * 8 + e][nl];
        *(uint4*)(dst + (size_t)nl * T_DIM + to * 8) = *(const uint4*)tmp;
    }
}

// ---- Kernel 3: per-chunk state U^T_i[d][n] = sum_{t in chunk i} Vt[d,t]*QRt[n,t] ----
// grid = 256 chunks * 8 n-tiles. Same row-row MFMA staging pattern as attn QK.
__global__ __launch_bounds__(256, 2)
void state_kernel(const u16* __restrict__ QRt, const u16* __restrict__ Vt,
                  u16* __restrict__ U) {
    __shared__ __align__(16) u16 Smem[16384];
    u16 (*As)[64] = (u16 (*)[64])Smem;            // Vt rows (d)
    u16 (*Bs)[64] = (u16 (*)[64])(Smem + 8192);   // QRt rows (n)

    const int ci = blockIdx.x >> 3;       // 0..255 (bh*16 + i)
    const int nt = blockIdx.x & 7;        // n-tile (128 wide)
    const int bh = ci >> 4;
    const int i  = ci & 15;

    const int tid  = threadIdx.x;
    const int w    = tid >> 6;
    const int wy   = w >> 1, wx = w & 1;
    const int lane = tid & 63;
    const int quad = lane >> 4;
    const int l15  = lane & 15;
    const int sw   = l15 & 7;
    const int srow = lane >> 3;
    const int scol = (lane & 7) ^ (srow & 7);

    const u16* Ap = Vt + (size_t)bh * ((size_t)D_DIM * T_DIM)
                       + (size_t)(w * 32 + srow) * T_DIM + i * 128 + scol * 8;
    const u16* Bp = QRt + (size_t)bh * ((size_t)N_DIM * T_DIM)
                        + (size_t)(nt * 128 + w * 32 + srow) * T_DIM + i * 128 + scol * 8;

    const f32x4 fz = {0.f, 0.f, 0.f, 0.f};
    f32x4 acc[4][4];
    #pragma unroll
    for (int mi = 0; mi < 4; ++mi)
        #pragma unroll
        for (int nj = 0; nj < 4; ++nj)
            acc[mi][nj] = fz;

    for (int kk = 0; kk < 128; kk += 64) {
        #pragma unroll
        for (int ii = 0; ii < 4; ++ii) {
            stage16(Ap + (size_t)ii * 8 * T_DIM + kk, &As[w * 32 + ii * 8][0]);
            stage16(Bp + (size_t)ii * 8 * T_DIM + kk, &Bs[w * 32 + ii * 8][0]);
        }
        __syncthreads();
        #pragma unroll
        for (int kc = 0; kc < 2; ++kc) {
            bf16x8 af[4], bfr[4];
            #pragma unroll
            for (int mi = 0; mi < 4; ++mi)
                af[mi] = *(const bf16x8*)((const char*)As + (wy * 64 + mi * 16 + l15) * 128 + (((kc * 4 + quad) ^ sw) << 4));
            #pragma unroll
            for (int nj = 0; nj < 4; ++nj)
                bfr[nj] = *(const bf16x8*)((const char*)Bs + (wx * 64 + nj * 16 + l15) * 128 + (((kc * 4 + quad) ^ sw) << 4));
            #pragma unroll
            for (int mi = 0; mi < 4; ++mi)
                #pragma unroll
                for (int nj = 0; nj < 4; ++nj)
                    acc[mi][nj] = __builtin_amdgcn_mfma_f32_16x16x32_bf16(af[mi], bfr[nj], acc[mi][nj], 0, 0, 0);
        }
        __syncthreads();
    }

    u16* ub = U + (size_t)ci * (128 * (size_t)N_DIM) + nt * 128;
    #pragma unroll
    for (int mi = 0; mi < 4; ++mi)
        #pragma unroll
        for (int nj = 0; nj < 4; ++nj)
            #pragma unroll
            for (int rr = 0; rr < 4; ++rr)
                ub[(size_t)(wy * 64 + mi * 16 + quad * 4 + rr) * N_DIM + wx * 64 + nj * 16 + l15]
                    = f32_to_bf16(acc[mi][nj][rr]);
}

// ---- Kernel 4: in-place exclusive prefix over chunk index (f32 accumulate) ----
// UP[ci][d][n] (bf16): after: UP[ci] = sum_{k<ci within same bh} U_k
__global__ void scan_kernel(u16* __restrict__ UP) {
    const int tg  = blockIdx.x * 256 + threadIdx.x;   // 262144 total
    const int bh  = tg >> 14;
    const int rem = tg & 16383;         // d(7b) | noct(7b)
    u16* base = UP + ((size_t)bh * 16 * 128 + (rem >> 7)) * N_DIM + (size_t)(rem & 127) * 8;
    float s[8];
    #pragma unroll
    for (int e = 0; e < 8; ++e) s[e] = 0.f;
    #pragma unroll 1
    for (int i = 0; i < 16; ++i) {
        u16* p = base + (size_t)i * (128 * (size_t)N_DIM);
        uint4 v = *(const uint4*)p;
        u16 in[8]; *(uint4*)in = v;
        u16 out[8];
        #pragma unroll
        for (int e = 0; e < 8; ++e) {
            float f = bf16_to_f32(in[e]);
            out[e]  = f32_to_bf16(s[e]);
            s[e]   += f;
        }
        *(uint4*)p = *(const uint4*)out;
    }
}

// ---- Kernel 5: chunked phase-C. b<256: main (QR_i @ P_i -> Part f32);
//      b>=256: intra (masked diag tile, exactly the old diagonal item -> Out). ----
__global__ __launch_bounds__(256, 2)
void attn2_kernel(const u16* __restrict__ QR, const u16* __restrict__ Pt,
                  const u16* __restrict__ Vt, float* __restrict__ Out,
                  float* __restrict__ Part) {
    __shared__ __align__(16) u16 Smem[17920];
    u16 (*As)[64]  = (u16 (*)[64])Smem;
    u16 (*Bs)[64]  = (u16 (*)[64])(Smem + 8192);
    u16 (*Ps)[140] = (u16 (*)[140])Smem;

    const int b = blockIdx.x;
    const bool is_main = b < 256;
    const int ci = is_main ? b : b - 256;
    const int bh = ci >> 4;
    const int i  = ci & 15;

    const int tid  = threadIdx.x;
    const int w    = tid >> 6;
    const int wy   = w >> 1, wx = w & 1;
    const int lane = tid & 63;
    const int quad = lane >> 4;
    const int l15  = lane & 15;
    const int sw   = l15 & 7;
    const int srow = lane >> 3;
    const int scol = (lane & 7) ^ (srow & 7);

    const u16* QRb = QR + (size_t)bh * ((size_t)T_DIM * N_DIM);
    const u16* Ap  = QRb + (size_t)(i * 128 + w * 32 + srow) * N_DIM + scol * 8;
    const u16* Bp  = is_main
        ? Pt + (size_t)(ci * 128 + w * 32 + srow) * N_DIM + scol * 8
        : Ap;

    const f32x4 fz = {0.f, 0.f, 0.f, 0.f};
    f32x4 s_acc[4][4];
    #pragma unroll
    for (int mi = 0; mi < 4; ++mi)
        #pragma unroll
        for (int nj = 0; nj < 4; ++nj)
            s_acc[mi][nj] = fz;

    for (int kk = 0; kk < N_DIM; kk += 64) {
        #pragma unroll
        for (int ii = 0; ii < 4; ++ii) {
            stage16(Ap + (size_t)ii * 8 * N_DIM + kk, &As[w * 32 + ii * 8][0]);
            stage16(Bp + (size_t)ii * 8 * N_DIM + kk, &Bs[w * 32 + ii * 8][0]);
        }
        __syncthreads();
        #pragma unroll
        for (int kc = 0; kc < 2; ++kc) {
            bf16x8 af[4], bfr[4];
            #pragma unroll
            for (int mi = 0; mi < 4; ++mi)
                af[mi] = *(const bf16x8*)((const char*)As + (wy * 64 + mi * 16 + l15) * 128 + (((kc * 4 + quad) ^ sw) << 4));
            #pragma unroll
            for (int nj = 0; nj < 4; ++nj)
                bfr[nj] = *(const bf16x8*)((const char*)Bs + (wx * 64 + nj * 16 + l15) * 128 + (((kc * 4 + quad) ^ sw) << 4));
            #pragma unroll
            for (int mi = 0; mi < 4; ++mi)
                #pragma unroll
                for (int nj = 0; nj < 4; ++nj)
                    s_acc[mi][nj] = __builtin_amdgcn_mfma_f32_16x16x32_bf16(af[mi], bfr[nj], s_acc[mi][nj], 0, 0, 0);
        }
        __syncthreads();
    }

    if (is_main) {
        // s_acc rows = t (within chunk), cols = d. Part linear == Out linear at ci base.
        float* pb = Part + (size_t)ci * 16384;
        #pragma unroll
        for (int mi = 0; mi < 4; ++mi)
            #pragma unroll
            for (int nj = 0; nj < 4; ++nj)
                #pragma unroll
                for (int rr = 0; rr < 4; ++rr)
                    pb[(wy * 64 + mi * 16 + quad * 4 + rr) * 128 + wx * 64 + nj * 16 + l15]
                        = s_acc[mi][nj][rr];
    } else {
        // strict causal on the diagonal tile: keep col < row
        #pragma unroll
        for (int mi = 0; mi < 4; ++mi) {
            const int rowb = wy * 64 + mi * 16 + quad * 4;
            #pragma unroll
            for (int nj = 0; nj < 4; ++nj) {
                const int col = wx * 64 + nj * 16 + l15;
                #pragma unroll
                for (int rr = 0; rr < 4; ++rr)
                    if (col >= rowb + rr) s_acc[mi][nj][rr] = 0.f;
            }
        }
        // C/D -> A-operand layout via LDS
        #pragma unroll
        for (int mi = 0; mi < 4; ++mi) {
            const int rowb = wy * 64 + mi * 16 + quad * 4;
            #pragma unroll
            for (int nj = 0; nj < 4; ++nj) {
                const int col = wx * 64 + nj * 16 + l15;
                #pragma unroll
                for (int rr = 0; rr < 4; ++rr)
                    Ps[rowb + rr][col] = f32_to_bf16(s_acc[mi][nj][rr]);
            }
        }
        __syncthreads();

        f32x4 o_acc[4][4];
        #pragma unroll
        for (int mi = 0; mi < 4; ++mi)
            #pragma unroll
            for (int nj = 0; nj < 4; ++nj)
                o_acc[mi][nj] = fz;

        const u16* vjb = Vt + (size_t)bh * ((size_t)D_DIM * T_DIM)
                            + (size_t)(wx * 64 + l15) * T_DIM + i * 128 + quad * 8;
        #pragma unroll
        for (int kc = 0; kc < 4; ++kc) {
            bf16x8 pf[4];
            #pragma unroll
            for (int mi = 0; mi < 4; ++mi)
                pf[mi] = *(const bf16x8*)(&Ps[wy * 64 + mi * 16 + l15][kc * 32 + quad * 8]);
            #pragma unroll
            for (int nj = 0; nj < 4; ++nj) {
                const bf16x8 vv = *(const bf16x8*)(vjb + (size_t)(nj * 16) * T_DIM + kc * 32);
                #pragma unroll
                for (int mi = 0; mi < 4; ++mi)
                    o_acc[mi][nj] = __builtin_amdgcn_mfma_f32_16x16x32_bf16(pf[mi], vv, o_acc[mi][nj], 0, 0, 0);
            }
        }

        float* ob = Out + ((size_t)bh * T_DIM + (size_t)i * 128) * D_DIM;
        #pragma unroll
        for (int mi = 0; mi < 4; ++mi)
            #pragma unroll
            for (int nj = 0; nj < 4; ++nj)
                #pragma unroll
                for (int rr = 0; rr < 4; ++rr)
                    ob[(size_t)(wy * 64 + mi * 16 + quad * 4 + rr) * D_DIM + wx * 64 + nj * 16 + l15]
                        = o_acc[mi][nj][rr];
    }
}

// ---- Kernel 6: Out += Part (identity linear mapping, float4 stream) ----
__global__ void combine2_kernel(float* __restrict__ Out, const float* __restrict__ Part) {
    const int idx = blockIdx.x * 256 + threadIdx.x;
    float4 a = ((float4*)Out)[idx];
    const float4 p = ((const float4*)Part)[idx];
    a.x += p.x; a.y += p.y; a.z += p.z; a.w += p.w;
    ((float4*)Out)[idx] = a;
}

// ======================= legacy fallback path (ws too small) =======================
__device__ __forceinline__ int run_start(int b) { return b < 128 ? 5 * b : 640 + 4 * (b - 128); }

__global__ __launch_bounds__(256, 2)
void attn_kernel(const u16* __restrict__ QR, const u16* __restrict__ Vt,
                 float* __restrict__ Out, u16* __restrict__ Part) {
    __shared__ __align__(16) u16 Smem[17920];
    u16 (*As)[64]  = (u16 (*)[64])Smem;
    u16 (*Bs)[64]  = (u16 (*)[64])(Smem + 8192);
    u16 (*Ps)[140] = (u16 (*)[140])Smem;

    const int b     = blockIdx.x;
    const int start = run_start(b);
    const int len   = b < 128 ? 5 : 4;

    const int tid  = threadIdx.x;
    const int w    = tid >> 6;
    const int wy   = w >> 1, wx = w & 1;
    const int lane = tid & 63;
    const int quad = lane >> 4;
    const int l15  = lane & 15;
    const int sw   = l15 & 7;
    const int srow = lane >> 3;
    const int scol = (lane & 7) ^ (srow & 7);

    const f32x4 fz = {0.f, 0.f, 0.f, 0.f};
    f32x4 o_acc[4][4];
    int cur_bh = -1, cur_qt = -1;
    bool hasj0 = false;
    const u16* QRb = QR;
    const u16* Ap  = QR;
    const u16* Vb  = Vt;

    for (int it = 0; it < len; ++it) {
        const int i = start + it;
        const int bh = i / 136;
        const int r  = i - bh * 136;
        int qt = 15, j = 0, acc = 0;
        #pragma unroll 1
        for (int q = 0; q < 16; ++q) {
            if (r < acc + q + 1) { qt = q; j = r - acc; break; }
            acc += q + 1;
        }

        if (qt != cur_qt || bh != cur_bh) {
            if (cur_qt >= 0) {
                if (hasj0) {
                    float* ob = Out + ((size_t)cur_bh * T_DIM + (size_t)cur_qt * 128) * D_DIM;
                    #pragma unroll
                    for (int mi = 0; mi < 4; ++mi)
                        #pragma unroll
                        for (int nj = 0; nj < 4; ++nj)
                            #pragma unroll
                            for (int rr = 0; rr < 4; ++rr)
                                ob[(size_t)(wy * 64 + mi * 16 + quad * 4 + rr) * D_DIM + wx * 64 + nj * 16 + l15] = o_acc[mi][nj][rr];
                } else {
                    u16* pb = Part + (size_t)b * 16384;
                    #pragma unroll
                    for (int mi = 0; mi < 4; ++mi)
                        #pragma unroll
                        for (int nj = 0; nj < 4; ++nj)
                            #pragma unroll
                            for (int rr = 0; rr < 4; ++rr)
                                pb[(wy * 64 + mi * 16 + quad * 4 + rr) * 128 + wx * 64 + nj * 16 + l15] = f32_to_bf16(o_acc[mi][nj][rr]);
                }
            }
            cur_bh = bh; cur_qt = qt; hasj0 = (j == 0);
            #pragma unroll
            for (int mi = 0; mi < 4; ++mi)
                #pragma unroll
                for (int nj = 0; nj < 4; ++nj)
                    o_acc[mi][nj] = fz;
            QRb = QR + (size_t)bh * (T_DIM * N_DIM);
            Ap  = QRb + (size_t)(qt * 128 + w * 32 + srow) * N_DIM + scol * 8;
            Vb  = Vt + (size_t)bh * (D_DIM * T_DIM) + (size_t)(wx * 64 + l15) * T_DIM + quad * 8;
        }

        const u16* Bp = QRb + (size_t)(j * 128 + w * 32 + srow) * N_DIM + scol * 8;
        f32x4 s_acc[4][4];
        #pragma unroll
        for (int mi = 0; mi < 4; ++mi)
            #pragma unroll
            for (int nj = 0; nj < 4; ++nj)
                s_acc[mi][nj] = fz;

        __syncthreads();

        for (int kk = 0; kk < N_DIM; kk += 64) {
            #pragma unroll
            for (int ii = 0; ii < 4; ++ii) {
                stage16(Ap + (size_t)ii * 8 * N_DIM + kk, &As[w * 32 + ii * 8][0]);
                stage16(Bp + (size_t)ii * 8 * N_DIM + kk, &Bs[w * 32 + ii * 8][0]);
            }
            __syncthreads();
            #pragma unroll
            for (int kc = 0; kc < 2; ++kc) {
                bf16x8 af[4], bfr[4];
                #pragma unroll
                for (int mi = 0; mi < 4; ++mi)
                    af[mi] = *(const bf16x8*)((const char*)As + (wy * 64 + mi * 16 + l15) * 128 + (((kc * 4 + quad) ^ sw) << 4));
                #pragma unroll
                for (int nj = 0; nj < 4; ++nj)
                    bfr[nj] = *(const bf16x8*)((const char*)Bs + (wx * 64 + nj * 16 + l15) * 128 + (((kc * 4 + quad) ^ sw) << 4));
                #pragma unroll
                for (int mi = 0; mi < 4; ++mi)
                    #pragma unroll
                    for (int nj = 0; nj < 4; ++nj)
                        s_acc[mi][nj] = __builtin_amdgcn_mfma_f32_16x16x32_bf16(af[mi], bfr[nj], s_acc[mi][nj], 0, 0, 0);
            }
            __syncthreads();
        }

        if (j == qt) {
            #pragma unroll
            for (int mi = 0; mi < 4; ++mi) {
                const int rowb = wy * 64 + mi * 16 + quad * 4;
                #pragma unroll
                for (int nj = 0; nj < 4; ++nj) {
                    const int col = wx * 64 + nj * 16 + l15;
                    #pragma unroll
                    for (int rr = 0; rr < 4; ++rr)
                        if (col >= rowb + rr) s_acc[mi][nj][rr] = 0.f;
                }
            }
        }

        #pragma unroll
        for (int mi = 0; mi < 4; ++mi) {
            const int rowb = wy * 64 + mi * 16 + quad * 4;
            #pragma unroll
            for (int nj = 0; nj < 4; ++nj) {
                const int col = wx * 64 + nj * 16 + l15;
                #pragma unroll
                for (int rr = 0; rr < 4; ++rr)
                    Ps[rowb + rr][col] = f32_to_bf16(s_acc[mi][nj][rr]);
            }
        }
        __syncthreads();

        const u16* vjb = Vb + j * 128;
        #pragma unroll
        for (int kc = 0; kc < 4; ++kc) {
            bf16x8 pf[4];
            #pragma unroll
            for (int mi = 0; mi < 4; ++mi)
                pf[mi] = *(const bf16x8*)(&Ps[wy * 64 + mi * 16 + l15][kc * 32 + quad * 8]);
            #pragma unroll
            for (int nj = 0; nj < 4; ++nj) {
                const bf16x8 vv = *(const bf16x8*)(vjb + (size_t)(nj * 16) * T_DIM + kc * 32);
                #pragma unroll
                for (int mi = 0; mi < 4; ++mi)
                    o_acc[mi][nj] = __builtin_amdgcn_mfma_f32_16x16x32_bf16(pf[mi], vv, o_acc[mi][nj], 0, 0, 0);
            }
        }
    }

    if (hasj0) {
        float* ob = Out + ((size_t)cur_bh * T_DIM + (size_t)cur_qt * 128) * D_DIM;
        #pragma unroll
        for (int mi = 0; mi < 4; ++mi)
            #pragma unroll
            for (int nj = 0; nj < 4; ++nj)
                #pragma unroll
                for (int rr = 0; rr < 4; ++rr)
                    ob[(size_t)(wy * 64 + mi * 16 + quad * 4 + rr) * D_DIM + wx * 64 + nj * 16 + l15] = o_acc[mi][nj][rr];
    } else {
        u16* pb = Part + (size_t)b * 16384;
        #pragma unroll
        for (int mi = 0; mi < 4; ++mi)
            #pragma unroll
            for (int nj = 0; nj < 4; ++nj)
                #pragma unroll
                for (int rr = 0; rr < 4; ++rr)
                    pb[(wy * 64 + mi * 16 + quad * 4 + rr) * 128 + wx * 64 + nj * 16 + l15] = f32_to_bf16(o_acc[mi][nj][rr]);
    }
}

__global__ void combine_kernel(float* __restrict__ Out, const u16* __restrict__ Part) {
    const int bh = blockIdx.x & 15;
    const int qt = 1 + (blockIdx.x >> 4);
    const int ts = bh * 136 + (qt * (qt + 1)) / 2;
    const int lo = ts + 1, hi = ts + qt;
    int bmin = (lo <= 640) ? (lo + 4) / 5 : 128 + (lo - 640 + 3) / 4;
    int writers[4], nw = 0;
    for (int bb = bmin; bb < 512 && run_start(bb) <= hi && nw < 4; ++bb)
        writers[nw++] = bb;
    if (nw == 0) return;
    float* ob = Out + ((size_t)bh * T_DIM + (size_t)qt * 128) * D_DIM;
    const int tid = threadIdx.x;
    #pragma unroll 1
    for (int e = 0; e < 64; ++e) {
        const int idx = e * 256 + tid;
        float a = ob[idx];
        for (int k = 0; k < nw; ++k)
            a += bf16_to_f32(Part[(size_t)writers[k] * 16384 + idx]);
        ob[idx] = a;
    }
}

extern "C" void kernel_launch(void* const* d_in, const int* in_sizes, int n_in,
                              void* d_out, int out_size, void* d_ws, size_t ws_size,
                              hipStream_t stream) {
    const float* Q = (const float*)d_in[0];
    const float* V = (const float*)d_in[2];   // d_in[1] is K == Q, unused
    float* Out = (float*)d_out;

    const size_t QR_E = (size_t)16 * T_DIM * N_DIM;   // 33,554,432 u16
    const size_t VT_E = (size_t)16 * D_DIM * T_DIM;   //  4,194,304 u16
    const size_t P_E  = (size_t)256 * 128 * N_DIM;    // 33,554,432 u16
    const size_t need = (QR_E * 2 + VT_E + P_E) * 2 + (size_t)256 * 16384 * 4;  // 226,492,416 B

    if (ws_size >= need) {
        // ws: QR | QRt | Vt | P(state, in-place scanned) | Part(f32)
        u16* QRw  = (u16*)d_ws;
        u16* QRtw = QRw + QR_E;
        u16* Vtw  = QRtw + QR_E;
        u16* Ptw  = Vtw + VT_E;
        float* PartF = (float*)(Ptw + P_E);

        rope_kernel<<<dim3(16384), dim3(256), 0, stream>>>(Q, QRw);
        vt_kernel<<<dim3(1024), dim3(256), 0, stream>>>(V, Vtw);
        qrt_kernel<<<dim3(8192), dim3(256), 0, stream>>>(QRw, QRtw);
        state_kernel<<<dim3(2048), dim3(256), 0, stream>>>(QRtw, Vtw, Ptw);
        scan_kernel<<<dim3(1024), dim3(256), 0, stream>>>(Ptw);
        attn2_kernel<<<dim3(512), dim3(256), 0, stream>>>(QRw, Ptw, Vtw, Out, PartF);
        combine2_kernel<<<dim3(4096), dim3(256), 0, stream>>>(Out, PartF);
    } else {
        // legacy path: QR | Vt | Part(bf16)
        u16* QRw  = (u16*)d_ws;
        u16* Vtw  = QRw + QR_E;
        u16* Part = Vtw + VT_E;

        rope_kernel<<<dim3(16384), dim3(256), 0, stream>>>(Q, QRw);
        vt_kernel<<<dim3(1024), dim3(256), 0, stream>>>(V, Vtw);
        attn_kernel<<<dim3(512), dim3(256), 0, stream>>>(QRw, Vtw, Out, Part);
        combine_kernel<<<dim3(240), dim3(256), 0, stream>>>(Out, Part);
    }
}

// Round 3
// 365.082 us; speedup vs baseline: 1.4442x; 1.0241x over previous
//
#include <hip/hip_runtime.h>

typedef __bf16 bf16_t;
typedef bf16_t bf16x8 __attribute__((ext_vector_type(8)));
typedef float f32x4 __attribute__((ext_vector_type(4)));
typedef unsigned short u16;
typedef unsigned int u32;

#define T_DIM 2048
#define N_DIM 1024
#define D_DIM 128

__device__ __forceinline__ u16 f32_to_bf16(float f) {
    u32 u = __builtin_bit_cast(u32, f);
    u += 0x7FFFu + ((u >> 16) & 1u);   // RNE
    return (u16)(u >> 16);
}
__device__ __forceinline__ float bf16_to_f32(u16 v) {
    u32 u = (u32)v << 16;
    return __builtin_bit_cast(float, u);
}

typedef __attribute__((address_space(1))) const u32 guint;
typedef __attribute__((address_space(3))) u32 luint;
// async global->LDS, 16B per lane, LDS dst = wave-uniform base + lane*16
__device__ __forceinline__ void stage16(const void* g, void* l) {
    __builtin_amdgcn_global_load_lds((guint*)g, (luint*)l, 16, 0, 0);
}
// T3/T4 minimum 2-phase: drain this iter's staging, then raw barrier.
__device__ __forceinline__ void wait_vm0_barrier() {
    asm volatile("s_waitcnt vmcnt(0)" ::: "memory");
    __builtin_amdgcn_s_barrier();
}

// ---- Kernel 1: fused RoPE + bf16 cast -> QR (t,n) AND QRt (n,t). ----
// grid = 16 bh * 32 t-tiles * 16 n-tiles, 64x64 tiles.
__global__ void ropet_kernel(const float* __restrict__ Q, u16* __restrict__ QR,
                             u16* __restrict__ QRt) {
    __shared__ u16 til[64][65];
    const int bh  = blockIdx.x >> 9;
    const int rem = blockIdx.x & 511;
    const int t0 = (rem >> 4) * 64, n0 = (rem & 15) * 64;
    const float* src = Q + (size_t)bh * ((size_t)T_DIM * N_DIM) + (size_t)t0 * N_DIM + n0;
    u16* qdst = QR + (size_t)bh * ((size_t)T_DIM * N_DIM) + (size_t)t0 * N_DIM + n0;
    #pragma unroll
    for (int k = 0; k < 4; ++k) {
        const int linear = k * 256 + threadIdx.x;
        const int r = linear >> 4;          // 0..63
        const int f = linear & 15;          // float4 index: cols f*4..f*4+3
        const float4 q = *(const float4*)(src + (size_t)r * N_DIM + f * 4);
        const int t = t0 + r;
        u16 o[4];
        #pragma unroll
        for (int pp = 0; pp < 2; ++pp) {
            const int pidx = ((n0 + f * 4) >> 1) + pp;   // pair index in [0,512)
            const float freq = exp2f((float)pidx * (-1.0f / 32.0f)) * 0.15915494309189535f;
            float ph = (float)t * freq;
            ph -= floorf(ph);
            const float s = __builtin_amdgcn_sinf(ph);
            const float c = __builtin_amdgcn_cosf(ph);
            const float a  = pp ? q.z : q.x;
            const float b2 = pp ? q.w : q.y;
            o[2 * pp]     = f32_to_bf16(a * c - b2 * s);
            o[2 * pp + 1] = f32_to_bf16(b2 * c + a * s);
        }
        *(uint2*)(qdst + (size_t)r * N_DIM + f * 4) = *(const uint2*)o;
        til[r][f * 4 + 0] = o[0]; til[r][f * 4 + 1] = o[1];
        til[r][f * 4 + 2] = o[2]; til[r][f * 4 + 3] = o[3];
    }
    __syncthreads();
    u16* tdst = QRt + (size_t)bh * ((size_t)N_DIM * T_DIM) + (size_t)n0 * T_DIM + t0;
    #pragma unroll
    for (int k = 0; k < 2; ++k) {
        const int linear = k * 256 + threadIdx.x;
        const int nl = linear >> 3, o = linear & 7;
        u16 tmp[8];
        #pragma unroll
        for (int e = 0; e < 8; ++e) tmp[e] = til[o * 8 + e][nl];
        *(uint4*)(tdst + (size_t)nl * T_DIM + o * 8) = *(const uint4*)tmp;
    }
}

// ---- Kernel 2: V -> bf16, transposed to Vt[bh][d][t] ----
__global__ void vt_kernel(const float* __restrict__ V, u16* __restrict__ Vt) {
    __shared__ u16 tile[64][65];
    const int bh   = blockIdx.x >> 6;
    const int rem  = blockIdx.x & 63;
    const int t0 = (rem >> 1) * 64, d0 = (rem & 1) * 64;
    const float* src = V + ((size_t)bh * T_DIM + t0) * D_DIM + d0;
    #pragma unroll
    for (int k = 0; k < 16; ++k) {
        int linear = k * 256 + threadIdx.x;
        int r = linear >> 6, c = linear & 63;
        tile[r][c] = f32_to_bf16(src[(size_t)r * D_DIM + c]);
    }
    __syncthreads();
    u16* dst = Vt + ((size_t)bh * D_DIM + d0) * T_DIM + t0;
    #pragma unroll
    for (int k = 0; k < 16; ++k) {
        int linear = k * 256 + threadIdx.x;
        int dr = linear >> 6, tc = linear & 63;
        dst[(size_t)dr * T_DIM + tc] = tile[tc][dr];
    }
}

// ---- Kernel 3: fused state+scan. One block per (bh, n-tile 128, d-tile 64). ----
// Iterates the 16 chunks sequentially; accumulator carries the running prefix.
// Before accumulating chunk ci, writes acc as the EXCLUSIVE prefix UP[ci] (bf16).
// 2-phase double-buffered staging (T3 minimum recipe).
__global__ __launch_bounds__(256, 1)
void statescan_kernel(const u16* __restrict__ QRt, const u16* __restrict__ Vt,
                      u16* __restrict__ UP) {
    // As[buf]: 64x64 @ Smem + buf*4096 ; Bs[buf]: 128x64 @ Smem + 8192 + buf*8192
    __shared__ __align__(16) u16 Smem[24576];

    const int b  = blockIdx.x;          // 16 bh * 8 nt * 2 dt
    const int bh = b >> 4;
    const int nt = (b >> 1) & 7;
    const int dt = b & 1;

    const int tid  = threadIdx.x;
    const int w    = tid >> 6;
    const int wy   = w >> 1, wx = w & 1;
    const int lane = tid & 63;
    const int quad = lane >> 4;
    const int l15  = lane & 15;
    const int sw   = l15 & 7;
    const int srow = lane >> 3;
    const int scol = (lane & 7) ^ (srow & 7);

    const u16* Ag = Vt  + (size_t)bh * ((size_t)D_DIM * T_DIM) + (size_t)(dt * 64)  * T_DIM;
    const u16* Bg = QRt + (size_t)bh * ((size_t)N_DIM * T_DIM) + (size_t)(nt * 128) * T_DIM;

    const f32x4 fz = {0.f, 0.f, 0.f, 0.f};
    f32x4 acc[2][4];
    #pragma unroll
    for (int mi = 0; mi < 2; ++mi)
        #pragma unroll
        for (int nj = 0; nj < 4; ++nj)
            acc[mi][nj] = fz;

    auto STAGE = [&](int buf, int s) {
        const int toff = s * 64;                     // 64 t per step, 2 steps/chunk
        #pragma unroll
        for (int ia = 0; ia < 2; ++ia)
            stage16(Ag + (size_t)(w * 16 + ia * 8 + srow) * T_DIM + toff + scol * 8,
                    Smem + buf * 4096 + (w * 16 + ia * 8) * 64);
        #pragma unroll
        for (int ib = 0; ib < 4; ++ib)
            stage16(Bg + (size_t)(w * 32 + ib * 8 + srow) * T_DIM + toff + scol * 8,
                    Smem + 8192 + buf * 8192 + (w * 32 + ib * 8) * 64);
    };

    u16* upb = UP + (size_t)(bh * 16) * (128 * (size_t)N_DIM)
                  + (size_t)(dt * 64) * N_DIM + nt * 128;

    auto WRITE_UP = [&](int ci) {
        u16* ub = upb + (size_t)ci * (128 * (size_t)N_DIM);
        #pragma unroll
        for (int mi = 0; mi < 2; ++mi)
            #pragma unroll
            for (int nj = 0; nj < 4; ++nj)
                #pragma unroll
                for (int rr = 0; rr < 4; ++rr)
                    ub[(size_t)(wy * 32 + mi * 16 + quad * 4 + rr) * N_DIM + wx * 64 + nj * 16 + l15]
                        = f32_to_bf16(acc[mi][nj][rr]);
    };

    STAGE(0, 0);
    wait_vm0_barrier();
    int buf = 0;
    // steps 0..29 accumulate chunks 0..14 (chunk 15's sum is never needed)
    for (int s = 0; s < 30; ++s) {
        if ((s & 1) == 0) WRITE_UP(s >> 1);          // exclusive prefix
        if (s < 29) STAGE(buf ^ 1, s + 1);
        const char* As = (const char*)(Smem + buf * 4096);
        const char* Bs = (const char*)(Smem + 8192 + buf * 8192);
        #pragma unroll
        for (int kc = 0; kc < 2; ++kc) {
            bf16x8 af[2], bfr[4];
            #pragma unroll
            for (int mi = 0; mi < 2; ++mi)
                af[mi] = *(const bf16x8*)(As + (wy * 32 + mi * 16 + l15) * 128 + (((kc * 4 + quad) ^ sw) << 4));
            #pragma unroll
            for (int nj = 0; nj < 4; ++nj)
                bfr[nj] = *(const bf16x8*)(Bs + (wx * 64 + nj * 16 + l15) * 128 + (((kc * 4 + quad) ^ sw) << 4));
            #pragma unroll
            for (int mi = 0; mi < 2; ++mi)
                #pragma unroll
                for (int nj = 0; nj < 4; ++nj)
                    acc[mi][nj] = __builtin_amdgcn_mfma_f32_16x16x32_bf16(af[mi], bfr[nj], acc[mi][nj], 0, 0, 0);
        }
        wait_vm0_barrier();
        buf ^= 1;
    }
    WRITE_UP(15);
}

// ---- Kernel 4: fused chunk kernel. One block per chunk ci = bh*16+i. ----
// Main (QR_i @ P_i^T, K=1024) and intra (QR_i @ QR_i^T) share the As tile:
// intra B-fragments are read from As rows. 2-phase pipelined staging.
// After K-loop: mask S (strict causal), Ps->PV accumulates into the main acc,
// single Out write. No Part, no combine.
__global__ __launch_bounds__(256, 1)
void attn3_kernel(const u16* __restrict__ QR, const u16* __restrict__ UP,
                  const u16* __restrict__ Vt, float* __restrict__ Out) {
    // As[buf]: 128x64 @ Smem + buf*8192 ; Bs[buf]: 128x64 @ Smem + 16384 + buf*8192
    __shared__ __align__(16) u16 Smem[32768];
    u16 (*Ps)[140] = (u16 (*)[140])Smem;    // aliased; used only after the K-loop

    const int b  = blockIdx.x;   // 0..255
    const int bh = b >> 4;
    const int i  = b & 15;

    const int tid  = threadIdx.x;
    const int w    = tid >> 6;
    const int wy   = w >> 1, wx = w & 1;
    const int lane = tid & 63;
    const int quad = lane >> 4;
    const int l15  = lane & 15;
    const int sw   = l15 & 7;
    const int srow = lane >> 3;
    const int scol = (lane & 7) ^ (srow & 7);

    const u16* Ap = QR + (size_t)bh * ((size_t)T_DIM * N_DIM)
                       + (size_t)(i * 128 + w * 32 + srow) * N_DIM + scol * 8;
    const u16* Bp = UP + (size_t)(b * 128 + w * 32 + srow) * N_DIM + scol * 8;

    const f32x4 fz = {0.f, 0.f, 0.f, 0.f};
    f32x4 sm[4][4], si[4][4];
    #pragma unroll
    for (int mi = 0; mi < 4; ++mi)
        #pragma unroll
        for (int nj = 0; nj < 4; ++nj) {
            sm[mi][nj] = fz;
            si[mi][nj] = fz;
        }

    auto STAGE = [&](int buf, int kk16) {
        const int kk = kk16 * 64;
        #pragma unroll
        for (int ii = 0; ii < 4; ++ii) {
            stage16(Ap + (size_t)(ii * 8) * N_DIM + kk, Smem + buf * 8192 + (w * 32 + ii * 8) * 64);
            stage16(Bp + (size_t)(ii * 8) * N_DIM + kk, Smem + 16384 + buf * 8192 + (w * 32 + ii * 8) * 64);
        }
    };

    STAGE(0, 0);
    wait_vm0_barrier();
    int buf = 0;
    for (int kk16 = 0; kk16 < 16; ++kk16) {
        if (kk16 < 15) STAGE(buf ^ 1, kk16 + 1);
        const char* As = (const char*)(Smem + buf * 8192);
        const char* Bs = (const char*)(Smem + 16384 + buf * 8192);
        #pragma unroll
        for (int kc = 0; kc < 2; ++kc) {
            bf16x8 af[4], bm[4], bi[4];
            #pragma unroll
            for (int mi = 0; mi < 4; ++mi)
                af[mi] = *(const bf16x8*)(As + (wy * 64 + mi * 16 + l15) * 128 + (((kc * 4 + quad) ^ sw) << 4));
            #pragma unroll
            for (int nj = 0; nj < 4; ++nj) {
                bm[nj] = *(const bf16x8*)(Bs + (wx * 64 + nj * 16 + l15) * 128 + (((kc * 4 + quad) ^ sw) << 4));
                bi[nj] = *(const bf16x8*)(As + (wx * 64 + nj * 16 + l15) * 128 + (((kc * 4 + quad) ^ sw) << 4));
            }
            #pragma unroll
            for (int mi = 0; mi < 4; ++mi)
                #pragma unroll
                for (int nj = 0; nj < 4; ++nj) {
                    sm[mi][nj] = __builtin_amdgcn_mfma_f32_16x16x32_bf16(af[mi], bm[nj], sm[mi][nj], 0, 0, 0);
                    si[mi][nj] = __builtin_amdgcn_mfma_f32_16x16x32_bf16(af[mi], bi[nj], si[mi][nj], 0, 0, 0);
                }
        }
        wait_vm0_barrier();
        buf ^= 1;
    }

    // strict causal on the diagonal tile: keep col < row
    #pragma unroll
    for (int mi = 0; mi < 4; ++mi) {
        const int rowb = wy * 64 + mi * 16 + quad * 4;
        #pragma unroll
        for (int nj = 0; nj < 4; ++nj) {
            const int col = wx * 64 + nj * 16 + l15;
            #pragma unroll
            for (int rr = 0; rr < 4; ++rr)
                if (col >= rowb + rr) si[mi][nj][rr] = 0.f;
        }
    }
    // C/D -> A-operand layout via LDS (cross-wave in wx => barrier both sides)
    #pragma unroll
    for (int mi = 0; mi < 4; ++mi) {
        const int rowb = wy * 64 + mi * 16 + quad * 4;
        #pragma unroll
        for (int nj = 0; nj < 4; ++nj) {
            const int col = wx * 64 + nj * 16 + l15;
            #pragma unroll
            for (int rr = 0; rr < 4; ++rr)
                Ps[rowb + rr][col] = f32_to_bf16(si[mi][nj][rr]);
        }
    }
    __syncthreads();

    const u16* vjb = Vt + (size_t)bh * ((size_t)D_DIM * T_DIM)
                        + (size_t)(wx * 64 + l15) * T_DIM + i * 128 + quad * 8;
    #pragma unroll
    for (int kc = 0; kc < 4; ++kc) {
        bf16x8 pf[4];
        #pragma unroll
        for (int mi = 0; mi < 4; ++mi)
            pf[mi] = *(const bf16x8*)(&Ps[wy * 64 + mi * 16 + l15][kc * 32 + quad * 8]);
        #pragma unroll
        for (int nj = 0; nj < 4; ++nj) {
            const bf16x8 vv = *(const bf16x8*)(vjb + (size_t)(nj * 16) * T_DIM + kc * 32);
            #pragma unroll
            for (int mi = 0; mi < 4; ++mi)
                sm[mi][nj] = __builtin_amdgcn_mfma_f32_16x16x32_bf16(pf[mi], vv, sm[mi][nj], 0, 0, 0);
        }
    }

    float* ob = Out + ((size_t)bh * T_DIM + (size_t)i * 128) * D_DIM;
    #pragma unroll
    for (int mi = 0; mi < 4; ++mi)
        #pragma unroll
        for (int nj = 0; nj < 4; ++nj)
            #pragma unroll
            for (int rr = 0; rr < 4; ++rr)
                ob[(size_t)(wy * 64 + mi * 16 + quad * 4 + rr) * D_DIM + wx * 64 + nj * 16 + l15]
                    = sm[mi][nj][rr];
}

// ======================= legacy fallback path (ws too small) =======================
__global__ void rope_kernel(const float* __restrict__ Q, u16* __restrict__ QR) {
    const int g = blockIdx.x * 256 + threadIdx.x;
    const int base = g * 4;
    const int t  = (base >> 9) & (T_DIM - 1);
    const int p0 = base & 511;
    const float4 qa = ((const float4*)Q)[g * 2];
    const float4 qb = ((const float4*)Q)[g * 2 + 1];
    const float vin[4][2] = {{qa.x, qa.y}, {qa.z, qa.w}, {qb.x, qb.y}, {qb.z, qb.w}};
    u16 ov[8];
    #pragma unroll
    for (int uu = 0; uu < 4; ++uu) {
        const float freq = exp2f((float)(p0 + uu) * (-1.0f / 32.0f)) * 0.15915494309189535f;
        float ph = (float)t * freq;
        ph = ph - floorf(ph);
        const float s = __builtin_amdgcn_sinf(ph);
        const float c = __builtin_amdgcn_cosf(ph);
        ov[2 * uu]     = f32_to_bf16(vin[uu][0] * c - vin[uu][1] * s);
        ov[2 * uu + 1] = f32_to_bf16(vin[uu][1] * c + vin[uu][0] * s);
    }
    ((uint4*)QR)[g] = *(const uint4*)ov;
}

__device__ __forceinline__ int run_start(int b) { return b < 128 ? 5 * b : 640 + 4 * (b - 128); }

__global__ __launch_bounds__(256, 2)
void attn_kernel(const u16* __restrict__ QR, const u16* __restrict__ Vt,
                 float* __restrict__ Out, u16* __restrict__ Part) {
    __shared__ __align__(16) u16 Smem[17920];
    u16 (*As)[64]  = (u16 (*)[64])Smem;
    u16 (*Bs)[64]  = (u16 (*)[64])(Smem + 8192);
    u16 (*Ps)[140] = (u16 (*)[140])Smem;

    const int b     = blockIdx.x;
    const int start = run_start(b);
    const int len   = b < 128 ? 5 : 4;

    const int tid  = threadIdx.x;
    const int w    = tid >> 6;
    const int wy   = w >> 1, wx = w & 1;
    const int lane = tid & 63;
    const int quad = lane >> 4;
    const int l15  = lane & 15;
    const int sw   = l15 & 7;
    const int srow = lane >> 3;
    const int scol = (lane & 7) ^ (srow & 7);

    const f32x4 fz = {0.f, 0.f, 0.f, 0.f};
    f32x4 o_acc[4][4];
    int cur_bh = -1, cur_qt = -1;
    bool hasj0 = false;
    const u16* QRb = QR;
    const u16* Ap  = QR;
    const u16* Vb  = Vt;

    for (int it = 0; it < len; ++it) {
        const int i = start + it;
        const int bh = i / 136;
        const int r  = i - bh * 136;
        int qt = 15, j = 0, acc = 0;
        #pragma unroll 1
        for (int q = 0; q < 16; ++q) {
            if (r < acc + q + 1) { qt = q; j = r - acc; break; }
            acc += q + 1;
        }

        if (qt != cur_qt || bh != cur_bh) {
            if (cur_qt >= 0) {
                if (hasj0) {
                    float* ob = Out + ((size_t)cur_bh * T_DIM + (size_t)cur_qt * 128) * D_DIM;
                    #pragma unroll
                    for (int mi = 0; mi < 4; ++mi)
                        #pragma unroll
                        for (int nj = 0; nj < 4; ++nj)
                            #pragma unroll
                            for (int rr = 0; rr < 4; ++rr)
                                ob[(size_t)(wy * 64 + mi * 16 + quad * 4 + rr) * D_DIM + wx * 64 + nj * 16 + l15] = o_acc[mi][nj][rr];
                } else {
                    u16* pb = Part + (size_t)b * 16384;
                    #pragma unroll
                    for (int mi = 0; mi < 4; ++mi)
                        #pragma unroll
                        for (int nj = 0; nj < 4; ++nj)
                            #pragma unroll
                            for (int rr = 0; rr < 4; ++rr)
                                pb[(wy * 64 + mi * 16 + quad * 4 + rr) * 128 + wx * 64 + nj * 16 + l15] = f32_to_bf16(o_acc[mi][nj][rr]);
                }
            }
            cur_bh = bh; cur_qt = qt; hasj0 = (j == 0);
            #pragma unroll
            for (int mi = 0; mi < 4; ++mi)
                #pragma unroll
                for (int nj = 0; nj < 4; ++nj)
                    o_acc[mi][nj] = fz;
            QRb = QR + (size_t)bh * (T_DIM * N_DIM);
            Ap  = QRb + (size_t)(qt * 128 + w * 32 + srow) * N_DIM + scol * 8;
            Vb  = Vt + (size_t)bh * (D_DIM * T_DIM) + (size_t)(wx * 64 + l15) * T_DIM + quad * 8;
        }

        const u16* Bp = QRb + (size_t)(j * 128 + w * 32 + srow) * N_DIM + scol * 8;
        f32x4 s_acc[4][4];
        #pragma unroll
        for (int mi = 0; mi < 4; ++mi)
            #pragma unroll
            for (int nj = 0; nj < 4; ++nj)
                s_acc[mi][nj] = fz;

        __syncthreads();

        for (int kk = 0; kk < N_DIM; kk += 64) {
            #pragma unroll
            for (int ii = 0; ii < 4; ++ii) {
                stage16(Ap + (size_t)ii * 8 * N_DIM + kk, &As[w * 32 + ii * 8][0]);
                stage16(Bp + (size_t)ii * 8 * N_DIM + kk, &Bs[w * 32 + ii * 8][0]);
            }
            __syncthreads();
            #pragma unroll
            for (int kc = 0; kc < 2; ++kc) {
                bf16x8 af[4], bfr[4];
                #pragma unroll
                for (int mi = 0; mi < 4; ++mi)
                    af[mi] = *(const bf16x8*)((const char*)As + (wy * 64 + mi * 16 + l15) * 128 + (((kc * 4 + quad) ^ sw) << 4));
                #pragma unroll
                for (int nj = 0; nj < 4; ++nj)
                    bfr[nj] = *(const bf16x8*)((const char*)Bs + (wx * 64 + nj * 16 + l15) * 128 + (((kc * 4 + quad) ^ sw) << 4));
                #pragma unroll
                for (int mi = 0; mi < 4; ++mi)
                    #pragma unroll
                    for (int nj = 0; nj < 4; ++nj)
                        s_acc[mi][nj] = __builtin_amdgcn_mfma_f32_16x16x32_bf16(af[mi], bfr[nj], s_acc[mi][nj], 0, 0, 0);
            }
            __syncthreads();
        }

        if (j == qt) {
            #pragma unroll
            for (int mi = 0; mi < 4; ++mi) {
                const int rowb = wy * 64 + mi * 16 + quad * 4;
                #pragma unroll
                for (int nj = 0; nj < 4; ++nj) {
                    const int col = wx * 64 + nj * 16 + l15;
                    #pragma unroll
                    for (int rr = 0; rr < 4; ++rr)
                        if (col >= rowb + rr) s_acc[mi][nj][rr] = 0.f;
                }
            }
        }

        #pragma unroll
        for (int mi = 0; mi < 4; ++mi) {
            const int rowb = wy * 64 + mi * 16 + quad * 4;
            #pragma unroll
            for (int nj = 0; nj < 4; ++nj) {
                const int col = wx * 64 + nj * 16 + l15;
                #pragma unroll
                for (int rr = 0; rr < 4; ++rr)
                    Ps[rowb + rr][col] = f32_to_bf16(s_acc[mi][nj][rr]);
            }
        }
        __syncthreads();

        const u16* vjb = Vb + j * 128;
        #pragma unroll
        for (int kc = 0; kc < 4; ++kc) {
            bf16x8 pf[4];
            #pragma unroll
            for (int mi = 0; mi < 4; ++mi)
                pf[mi] = *(const bf16x8*)(&Ps[wy * 64 + mi * 16 + l15][kc * 32 + quad * 8]);
            #pragma unroll
            for (int nj = 0; nj < 4; ++nj) {
                const bf16x8 vv = *(const bf16x8*)(vjb + (size_t)(nj * 16) * T_DIM + kc * 32);
                #pragma unroll
                for (int mi = 0; mi < 4; ++mi)
                    o_acc[mi][nj] = __builtin_amdgcn_mfma_f32_16x16x32_bf16(pf[mi], vv, o_acc[mi][nj], 0, 0, 0);
            }
        }
    }

    if (hasj0) {
        float* ob = Out + ((size_t)cur_bh * T_DIM + (size_t)cur_qt * 128) * D_DIM;
        #pragma unroll
        for (int mi = 0; mi < 4; ++mi)
            #pragma unroll
            for (int nj = 0; nj < 4; ++nj)
                #pragma unroll
                for (int rr = 0; rr < 4; ++rr)
                    ob[(size_t)(wy * 64 + mi * 16 + quad * 4 + rr) * D_DIM + wx * 64 + nj * 16 + l15] = o_acc[mi][nj][rr];
    } else {
        u16* pb = Part + (size_t)b * 16384;
        #pragma unroll
        for (int mi = 0; mi < 4; ++mi)
            #pragma unroll
            for (int nj = 0; nj < 4; ++nj)
                #pragma unroll
                for (int rr = 0; rr < 4; ++rr)
                    pb[(wy * 64 + mi * 16 + quad * 4 + rr) * 128 + wx * 64 + nj * 16 + l15] = f32_to_bf16(o_acc[mi][nj][rr]);
    }
}

__global__ void combine_kernel(float* __restrict__ Out, const u16* __restrict__ Part) {
    const int bh = blockIdx.x & 15;
    const int qt = 1 + (blockIdx.x >> 4);
    const int ts = bh * 136 + (qt * (qt + 1)) / 2;
    const int lo = ts + 1, hi = ts + qt;
    int bmin = (lo <= 640) ? (lo + 4) / 5 : 128 + (lo - 640 + 3) / 4;
    int writers[4], nw = 0;
    for (int bb = bmin; bb < 512 && run_start(bb) <= hi && nw < 4; ++bb)
        writers[nw++] = bb;
    if (nw == 0) return;
    float* ob = Out + ((size_t)bh * T_DIM + (size_t)qt * 128) * D_DIM;
    const int tid = threadIdx.x;
    #pragma unroll 1
    for (int e = 0; e < 64; ++e) {
        const int idx = e * 256 + tid;
        float a = ob[idx];
        for (int k = 0; k < nw; ++k)
            a += bf16_to_f32(Part[(size_t)writers[k] * 16384 + idx]);
        ob[idx] = a;
    }
}

extern "C" void kernel_launch(void* const* d_in, const int* in_sizes, int n_in,
                              void* d_out, int out_size, void* d_ws, size_t ws_size,
                              hipStream_t stream) {
    const float* Q = (const float*)d_in[0];
    const float* V = (const float*)d_in[2];   // d_in[1] is K == Q, unused
    float* Out = (float*)d_out;

    const size_t QR_E = (size_t)16 * T_DIM * N_DIM;   // 33,554,432 u16
    const size_t VT_E = (size_t)16 * D_DIM * T_DIM;   //  4,194,304 u16
    const size_t UP_E = (size_t)256 * 128 * N_DIM;    // 33,554,432 u16
    const size_t need = (QR_E * 2 + VT_E + UP_E) * 2; // 209,715,200 B

    if (ws_size >= need) {
        // ws: QR | QRt | Vt | UP (exclusive-prefix state, bf16)
        u16* QRw  = (u16*)d_ws;
        u16* QRtw = QRw + QR_E;
        u16* Vtw  = QRtw + QR_E;
        u16* UPw  = Vtw + VT_E;

        ropet_kernel<<<dim3(8192), dim3(256), 0, stream>>>(Q, QRw, QRtw);
        vt_kernel<<<dim3(1024), dim3(256), 0, stream>>>(V, Vtw);
        statescan_kernel<<<dim3(256), dim3(256), 0, stream>>>(QRtw, Vtw, UPw);
        attn3_kernel<<<dim3(256), dim3(256), 0, stream>>>(QRw, UPw, Vtw, Out);
    } else {
        // legacy path: QR | Vt | Part(bf16)
        u16* QRw  = (u16*)d_ws;
        u16* Vtw  = QRw + QR_E;
        u16* Part = Vtw + VT_E;

        rope_kernel<<<dim3(16384), dim3(256), 0, stream>>>(Q, QRw);
        vt_kernel<<<dim3(1024), dim3(256), 0, stream>>>(V, Vtw);
        attn_kernel<<<dim3(512), dim3(256), 0, stream>>>(QRw, Vtw, Out, Part);
        combine_kernel<<<dim3(240), dim3(256), 0, stream>>>(Out, Part);
    }
}

// Round 4
// 362.884 us; speedup vs baseline: 1.4529x; 1.0061x over previous
//
#include <hip/hip_runtime.h>

typedef __bf16 bf16_t;
typedef bf16_t bf16x8 __attribute__((ext_vector_type(8)));
typedef float f32x4 __attribute__((ext_vector_type(4)));
typedef unsigned short u16;
typedef unsigned int u32;

#define T_DIM 2048
#define N_DIM 1024
#define D_DIM 128

__device__ __forceinline__ u16 f32_to_bf16(float f) {
    u32 u = __builtin_bit_cast(u32, f);
    u += 0x7FFFu + ((u >> 16) & 1u);   // RNE
    return (u16)(u >> 16);
}
__device__ __forceinline__ float bf16_to_f32(u16 v) {
    u32 u = (u32)v << 16;
    return __builtin_bit_cast(float, u);
}

typedef __attribute__((address_space(1))) const u32 guint;
typedef __attribute__((address_space(3))) u32 luint;
// async global->LDS, 16B per lane, LDS dst = wave-uniform base + lane*16
__device__ __forceinline__ void stage16(const void* g, void* l) {
    __builtin_amdgcn_global_load_lds((guint*)g, (luint*)l, 16, 0, 0);
}
// T3/T4 minimum 2-phase: drain this iter's staging, then raw barrier.
__device__ __forceinline__ void wait_vm0_barrier() {
    asm volatile("s_waitcnt vmcnt(0)" ::: "memory");
    __builtin_amdgcn_s_barrier();
}

// ---- Kernel 1: fused RoPE + bf16 cast -> QR (t,n) AND QRt (n,t), v2. ----
// 64t x 128n tiles, 4096 blocks. uint4 QR stores, b128 LDS writes with
// row-XOR swizzle key ((t>>3)&7)<<3 so phase-2 column reads are ~2-way.
__global__ void ropet_kernel(const float* __restrict__ Q, u16* __restrict__ QR,
                             u16* __restrict__ QRt) {
    __shared__ __align__(16) u16 til[64][136];
    const int bh  = blockIdx.x >> 8;
    const int rem = blockIdx.x & 255;
    const int t0 = (rem >> 3) * 64, n0 = (rem & 7) * 128;
    const float* src = Q + (size_t)bh * ((size_t)T_DIM * N_DIM) + (size_t)t0 * N_DIM + n0;
    u16* qdst = QR + (size_t)bh * ((size_t)T_DIM * N_DIM) + (size_t)t0 * N_DIM + n0;
    #pragma unroll
    for (int k = 0; k < 4; ++k) {
        const int slot = k * 256 + threadIdx.x;
        const int r  = slot >> 4;           // 0..63
        const int f8 = slot & 15;           // col octet: cols f8*8..f8*8+7
        const float4 qa = *(const float4*)(src + (size_t)r * N_DIM + f8 * 8);
        const float4 qb = *(const float4*)(src + (size_t)r * N_DIM + f8 * 8 + 4);
        const float vin[4][2] = {{qa.x, qa.y}, {qa.z, qa.w}, {qb.x, qb.y}, {qb.z, qb.w}};
        const int t = t0 + r;
        u16 ov[8];
        #pragma unroll
        for (int pp = 0; pp < 4; ++pp) {
            const int pidx = (n0 >> 1) + f8 * 4 + pp;   // pair index in [0,512)
            const float freq = exp2f((float)pidx * (-1.0f / 32.0f)) * 0.15915494309189535f;
            float ph = (float)t * freq;
            ph -= floorf(ph);
            const float s = __builtin_amdgcn_sinf(ph);
            const float c = __builtin_amdgcn_cosf(ph);
            ov[2 * pp]     = f32_to_bf16(vin[pp][0] * c - vin[pp][1] * s);
            ov[2 * pp + 1] = f32_to_bf16(vin[pp][1] * c + vin[pp][0] * s);
        }
        *(uint4*)(qdst + (size_t)r * N_DIM + f8 * 8) = *(const uint4*)ov;
        *(uint4*)(&til[r][(f8 * 8) ^ (((r >> 3) & 7) << 3)]) = *(const uint4*)ov;
    }
    __syncthreads();
    u16* tdst = QRt + (size_t)bh * ((size_t)N_DIM * T_DIM) + (size_t)n0 * T_DIM + t0;
    #pragma unroll
    for (int k = 0; k < 4; ++k) {
        const int slot = k * 256 + threadIdx.x;
        const int nl = slot >> 3;           // 0..127
        const int t8 = slot & 7;            // t octet
        u16 ov2[8];
        #pragma unroll
        for (int e = 0; e < 8; ++e)
            ov2[e] = til[t8 * 8 + e][nl ^ (t8 << 3)];
        *(uint4*)(tdst + (size_t)nl * T_DIM + t8 * 8) = *(const uint4*)ov2;
    }
}

// ---- Kernel 2: V -> bf16, transposed to Vt[bh][d][t] ----
__global__ void vt_kernel(const float* __restrict__ V, u16* __restrict__ Vt) {
    __shared__ u16 tile[64][65];
    const int bh   = blockIdx.x >> 6;
    const int rem  = blockIdx.x & 63;
    const int t0 = (rem >> 1) * 64, d0 = (rem & 1) * 64;
    const float* src = V + ((size_t)bh * T_DIM + t0) * D_DIM + d0;
    #pragma unroll
    for (int k = 0; k < 16; ++k) {
        int linear = k * 256 + threadIdx.x;
        int r = linear >> 6, c = linear & 63;
        tile[r][c] = f32_to_bf16(src[(size_t)r * D_DIM + c]);
    }
    __syncthreads();
    u16* dst = Vt + ((size_t)bh * D_DIM + d0) * T_DIM + t0;
    #pragma unroll
    for (int k = 0; k < 16; ++k) {
        int linear = k * 256 + threadIdx.x;
        int dr = linear >> 6, tc = linear & 63;
        dst[(size_t)dr * T_DIM + tc] = tile[tc][dr];
    }
}

// ---- Kernel 3: fused state+scan, 512 threads (8 waves, 2 waves/SIMD). ----
// One block per (bh, n-tile 128, d-tile 64). Sequential over 16 chunks;
// accumulator carries the running prefix; writes EXCLUSIVE prefix UP[ci].
__global__ __launch_bounds__(512, 2)
void statescan_kernel(const u16* __restrict__ QRt, const u16* __restrict__ Vt,
                      u16* __restrict__ UP) {
    // As[buf]: 64x64 @ Smem + buf*4096 ; Bs[buf]: 128x64 @ Smem + 8192 + buf*8192 (u16 units)
    __shared__ __align__(16) u16 Smem[24576];

    const int b  = blockIdx.x;          // 16 bh * 8 nt * 2 dt
    const int bh = b >> 4;
    const int nt = (b >> 1) & 7;
    const int dt = b & 1;

    const int tid  = threadIdx.x;
    const int w    = tid >> 6;           // 0..7
    const int wy   = w >> 1, wx = w & 1; // wy 0..3
    const int lane = tid & 63;
    const int quad = lane >> 4;
    const int l15  = lane & 15;
    const int sw   = l15 & 7;
    const int srow = lane >> 3;
    const int scol = (lane & 7) ^ (srow & 7);

    const u16* Ag = Vt  + (size_t)bh * ((size_t)D_DIM * T_DIM) + (size_t)(dt * 64)  * T_DIM;
    const u16* Bg = QRt + (size_t)bh * ((size_t)N_DIM * T_DIM) + (size_t)(nt * 128) * T_DIM;

    const f32x4 fz = {0.f, 0.f, 0.f, 0.f};
    f32x4 acc[4];
    #pragma unroll
    for (int nj = 0; nj < 4; ++nj) acc[nj] = fz;

    auto STAGE = [&](int buf, int s) {
        const int toff = s * 64;                     // 64 t per step, 2 steps/chunk
        if (w < 4) {
            #pragma unroll
            for (int ia = 0; ia < 2; ++ia)
                stage16(Ag + (size_t)(w * 16 + ia * 8 + srow) * T_DIM + toff + scol * 8,
                        Smem + buf * 4096 + (w * 16 + ia * 8) * 64);
        }
        #pragma unroll
        for (int ib = 0; ib < 2; ++ib)
            stage16(Bg + (size_t)(w * 16 + ib * 8 + srow) * T_DIM + toff + scol * 8,
                    Smem + 8192 + buf * 8192 + (w * 16 + ib * 8) * 64);
    };

    u16* upb = UP + (size_t)(bh * 16) * (128 * (size_t)N_DIM)
                  + (size_t)(dt * 64) * N_DIM + nt * 128;

    auto WRITE_UP = [&](int ci) {
        u16* ub = upb + (size_t)ci * (128 * (size_t)N_DIM);
        #pragma unroll
        for (int nj = 0; nj < 4; ++nj)
            #pragma unroll
            for (int rr = 0; rr < 4; ++rr)
                ub[(size_t)(wy * 16 + quad * 4 + rr) * N_DIM + wx * 64 + nj * 16 + l15]
                    = f32_to_bf16(acc[nj][rr]);
    };

    STAGE(0, 0);
    wait_vm0_barrier();
    int buf = 0;
    // steps 0..29 accumulate chunks 0..14 (chunk 15's sum is never needed)
    for (int s = 0; s < 30; ++s) {
        if ((s & 1) == 0) WRITE_UP(s >> 1);          // exclusive prefix
        if (s < 29) STAGE(buf ^ 1, s + 1);
        const char* As = (const char*)(Smem + buf * 4096);
        const char* Bs = (const char*)(Smem + 8192 + buf * 8192);
        #pragma unroll
        for (int kc = 0; kc < 2; ++kc) {
            bf16x8 af, bfr[4];
            af = *(const bf16x8*)(As + (wy * 16 + l15) * 128 + (((kc * 4 + quad) ^ sw) << 4));
            #pragma unroll
            for (int nj = 0; nj < 4; ++nj)
                bfr[nj] = *(const bf16x8*)(Bs + (wx * 64 + nj * 16 + l15) * 128 + (((kc * 4 + quad) ^ sw) << 4));
            #pragma unroll
            for (int nj = 0; nj < 4; ++nj)
                acc[nj] = __builtin_amdgcn_mfma_f32_16x16x32_bf16(af, bfr[nj], acc[nj], 0, 0, 0);
        }
        wait_vm0_barrier();
        buf ^= 1;
    }
    WRITE_UP(15);
}

// ---- Kernel 4: fused chunk kernel, 512 threads (8 waves). One block per chunk. ----
// Main (QR_i @ P_i^T, K=1024) and intra (QR_i @ QR_i^T) share the As tile.
// After K-loop: mask S (strict causal), Ps->PV accumulates into main acc, single Out write.
__global__ __launch_bounds__(512, 2)
void attn3_kernel(const u16* __restrict__ QR, const u16* __restrict__ UP,
                  const u16* __restrict__ Vt, float* __restrict__ Out) {
    // As[buf]: 128x64 @ Smem + buf*8192 ; Bs[buf]: 128x64 @ Smem + 16384 + buf*8192 (u16 units)
    __shared__ __align__(16) u16 Smem[32768];
    u16 (*Ps)[140] = (u16 (*)[140])Smem;    // aliased; used only after the K-loop

    // bijective XCD swizzle (nwg=256, 256%8==0): group blocks sharing bh per XCD
    const int b  = (blockIdx.x & 7) * 32 + (blockIdx.x >> 3);   // 0..255
    const int bh = b >> 4;
    const int i  = b & 15;

    const int tid  = threadIdx.x;
    const int w    = tid >> 6;           // 0..7
    const int wy   = w >> 1, wx = w & 1; // wy 0..3
    const int lane = tid & 63;
    const int quad = lane >> 4;
    const int l15  = lane & 15;
    const int sw   = l15 & 7;
    const int srow = lane >> 3;
    const int scol = (lane & 7) ^ (srow & 7);

    const u16* Ap = QR + (size_t)bh * ((size_t)T_DIM * N_DIM)
                       + (size_t)(i * 128 + w * 16 + srow) * N_DIM + scol * 8;
    const u16* Bp = UP + (size_t)(b * 128 + w * 16 + srow) * N_DIM + scol * 8;

    const f32x4 fz = {0.f, 0.f, 0.f, 0.f};
    f32x4 sm[2][4], si[2][4];
    #pragma unroll
    for (int mi = 0; mi < 2; ++mi)
        #pragma unroll
        for (int nj = 0; nj < 4; ++nj) {
            sm[mi][nj] = fz;
            si[mi][nj] = fz;
        }

    auto STAGE = [&](int buf, int kk16) {
        const int kk = kk16 * 64;
        #pragma unroll
        for (int ii = 0; ii < 2; ++ii) {
            stage16(Ap + (size_t)(ii * 8) * N_DIM + kk, Smem + buf * 8192 + (w * 16 + ii * 8) * 64);
            stage16(Bp + (size_t)(ii * 8) * N_DIM + kk, Smem + 16384 + buf * 8192 + (w * 16 + ii * 8) * 64);
        }
    };

    STAGE(0, 0);
    wait_vm0_barrier();
    int buf = 0;
    for (int kk16 = 0; kk16 < 16; ++kk16) {
        if (kk16 < 15) STAGE(buf ^ 1, kk16 + 1);
        const char* As = (const char*)(Smem + buf * 8192);
        const char* Bs = (const char*)(Smem + 16384 + buf * 8192);
        #pragma unroll
        for (int kc = 0; kc < 2; ++kc) {
            bf16x8 af[2], bm[4], bi[4];
            #pragma unroll
            for (int mi = 0; mi < 2; ++mi)
                af[mi] = *(const bf16x8*)(As + (wy * 32 + mi * 16 + l15) * 128 + (((kc * 4 + quad) ^ sw) << 4));
            #pragma unroll
            for (int nj = 0; nj < 4; ++nj) {
                bm[nj] = *(const bf16x8*)(Bs + (wx * 64 + nj * 16 + l15) * 128 + (((kc * 4 + quad) ^ sw) << 4));
                bi[nj] = *(const bf16x8*)(As + (wx * 64 + nj * 16 + l15) * 128 + (((kc * 4 + quad) ^ sw) << 4));
            }
            #pragma unroll
            for (int mi = 0; mi < 2; ++mi)
                #pragma unroll
                for (int nj = 0; nj < 4; ++nj) {
                    sm[mi][nj] = __builtin_amdgcn_mfma_f32_16x16x32_bf16(af[mi], bm[nj], sm[mi][nj], 0, 0, 0);
                    si[mi][nj] = __builtin_amdgcn_mfma_f32_16x16x32_bf16(af[mi], bi[nj], si[mi][nj], 0, 0, 0);
                }
        }
        wait_vm0_barrier();
        buf ^= 1;
    }

    // strict causal on the diagonal tile: keep col < row
    #pragma unroll
    for (int mi = 0; mi < 2; ++mi) {
        const int rowb = wy * 32 + mi * 16 + quad * 4;
        #pragma unroll
        for (int nj = 0; nj < 4; ++nj) {
            const int col = wx * 64 + nj * 16 + l15;
            #pragma unroll
            for (int rr = 0; rr < 4; ++rr)
                if (col >= rowb + rr) si[mi][nj][rr] = 0.f;
        }
    }
    // C/D -> A-operand layout via LDS (cross-wave in wx => barrier both sides)
    #pragma unroll
    for (int mi = 0; mi < 2; ++mi) {
        const int rowb = wy * 32 + mi * 16 + quad * 4;
        #pragma unroll
        for (int nj = 0; nj < 4; ++nj) {
            const int col = wx * 64 + nj * 16 + l15;
            #pragma unroll
            for (int rr = 0; rr < 4; ++rr)
                Ps[rowb + rr][col] = f32_to_bf16(si[mi][nj][rr]);
        }
    }
    __syncthreads();

    const u16* vjb = Vt + (size_t)bh * ((size_t)D_DIM * T_DIM)
                        + (size_t)(wx * 64 + l15) * T_DIM + i * 128 + quad * 8;
    #pragma unroll
    for (int kc = 0; kc < 4; ++kc) {
        bf16x8 pf[2];
        #pragma unroll
        for (int mi = 0; mi < 2; ++mi)
            pf[mi] = *(const bf16x8*)(&Ps[wy * 32 + mi * 16 + l15][kc * 32 + quad * 8]);
        #pragma unroll
        for (int nj = 0; nj < 4; ++nj) {
            const bf16x8 vv = *(const bf16x8*)(vjb + (size_t)(nj * 16) * T_DIM + kc * 32);
            #pragma unroll
            for (int mi = 0; mi < 2; ++mi)
                sm[mi][nj] = __builtin_amdgcn_mfma_f32_16x16x32_bf16(pf[mi], vv, sm[mi][nj], 0, 0, 0);
        }
    }

    float* ob = Out + ((size_t)bh * T_DIM + (size_t)i * 128) * D_DIM;
    #pragma unroll
    for (int mi = 0; mi < 2; ++mi)
        #pragma unroll
        for (int nj = 0; nj < 4; ++nj)
            #pragma unroll
            for (int rr = 0; rr < 4; ++rr)
                ob[(size_t)(wy * 32 + mi * 16 + quad * 4 + rr) * D_DIM + wx * 64 + nj * 16 + l15]
                    = sm[mi][nj][rr];
}

// ======================= legacy fallback path (ws too small) =======================
__global__ void rope_kernel(const float* __restrict__ Q, u16* __restrict__ QR) {
    const int g = blockIdx.x * 256 + threadIdx.x;
    const int base = g * 4;
    const int t  = (base >> 9) & (T_DIM - 1);
    const int p0 = base & 511;
    const float4 qa = ((const float4*)Q)[g * 2];
    const float4 qb = ((const float4*)Q)[g * 2 + 1];
    const float vin[4][2] = {{qa.x, qa.y}, {qa.z, qa.w}, {qb.x, qb.y}, {qb.z, qb.w}};
    u16 ov[8];
    #pragma unroll
    for (int uu = 0; uu < 4; ++uu) {
        const float freq = exp2f((float)(p0 + uu) * (-1.0f / 32.0f)) * 0.15915494309189535f;
        float ph = (float)t * freq;
        ph = ph - floorf(ph);
        const float s = __builtin_amdgcn_sinf(ph);
        const float c = __builtin_amdgcn_cosf(ph);
        ov[2 * uu]     = f32_to_bf16(vin[uu][0] * c - vin[uu][1] * s);
        ov[2 * uu + 1] = f32_to_bf16(vin[uu][1] * c + vin[uu][0] * s);
    }
    ((uint4*)QR)[g] = *(const uint4*)ov;
}

__device__ __forceinline__ int run_start(int b) { return b < 128 ? 5 * b : 640 + 4 * (b - 128); }

__global__ __launch_bounds__(256, 2)
void attn_kernel(const u16* __restrict__ QR, const u16* __restrict__ Vt,
                 float* __restrict__ Out, u16* __restrict__ Part) {
    __shared__ __align__(16) u16 Smem[17920];
    u16 (*As)[64]  = (u16 (*)[64])Smem;
    u16 (*Bs)[64]  = (u16 (*)[64])(Smem + 8192);
    u16 (*Ps)[140] = (u16 (*)[140])Smem;

    const int b     = blockIdx.x;
    const int start = run_start(b);
    const int len   = b < 128 ? 5 : 4;

    const int tid  = threadIdx.x;
    const int w    = tid >> 6;
    const int wy   = w >> 1, wx = w & 1;
    const int lane = tid & 63;
    const int quad = lane >> 4;
    const int l15  = lane & 15;
    const int sw   = l15 & 7;
    const int srow = lane >> 3;
    const int scol = (lane & 7) ^ (srow & 7);

    const f32x4 fz = {0.f, 0.f, 0.f, 0.f};
    f32x4 o_acc[4][4];
    int cur_bh = -1, cur_qt = -1;
    bool hasj0 = false;
    const u16* QRb = QR;
    const u16* Ap  = QR;
    const u16* Vb  = Vt;

    for (int it = 0; it < len; ++it) {
        const int i = start + it;
        const int bh = i / 136;
        const int r  = i - bh * 136;
        int qt = 15, j = 0, acc = 0;
        #pragma unroll 1
        for (int q = 0; q < 16; ++q) {
            if (r < acc + q + 1) { qt = q; j = r - acc; break; }
            acc += q + 1;
        }

        if (qt != cur_qt || bh != cur_bh) {
            if (cur_qt >= 0) {
                if (hasj0) {
                    float* ob = Out + ((size_t)cur_bh * T_DIM + (size_t)cur_qt * 128) * D_DIM;
                    #pragma unroll
                    for (int mi = 0; mi < 4; ++mi)
                        #pragma unroll
                        for (int nj = 0; nj < 4; ++nj)
                            #pragma unroll
                            for (int rr = 0; rr < 4; ++rr)
                                ob[(size_t)(wy * 64 + mi * 16 + quad * 4 + rr) * D_DIM + wx * 64 + nj * 16 + l15] = o_acc[mi][nj][rr];
                } else {
                    u16* pb = Part + (size_t)b * 16384;
                    #pragma unroll
                    for (int mi = 0; mi < 4; ++mi)
                        #pragma unroll
                        for (int nj = 0; nj < 4; ++nj)
                            #pragma unroll
                            for (int rr = 0; rr < 4; ++rr)
                                pb[(wy * 64 + mi * 16 + quad * 4 + rr) * 128 + wx * 64 + nj * 16 + l15] = f32_to_bf16(o_acc[mi][nj][rr]);
                }
            }
            cur_bh = bh; cur_qt = qt; hasj0 = (j == 0);
            #pragma unroll
            for (int mi = 0; mi < 4; ++mi)
                #pragma unroll
                for (int nj = 0; nj < 4; ++nj)
                    o_acc[mi][nj] = fz;
            QRb = QR + (size_t)bh * (T_DIM * N_DIM);
            Ap  = QRb + (size_t)(qt * 128 + w * 32 + srow) * N_DIM + scol * 8;
            Vb  = Vt + (size_t)bh * (D_DIM * T_DIM) + (size_t)(wx * 64 + l15) * T_DIM + quad * 8;
        }

        const u16* Bp = QRb + (size_t)(j * 128 + w * 32 + srow) * N_DIM + scol * 8;
        f32x4 s_acc[4][4];
        #pragma unroll
        for (int mi = 0; mi < 4; ++mi)
            #pragma unroll
            for (int nj = 0; nj < 4; ++nj)
                s_acc[mi][nj] = fz;

        __syncthreads();

        for (int kk = 0; kk < N_DIM; kk += 64) {
            #pragma unroll
            for (int ii = 0; ii < 4; ++ii) {
                stage16(Ap + (size_t)ii * 8 * N_DIM + kk, &As[w * 32 + ii * 8][0]);
                stage16(Bp + (size_t)ii * 8 * N_DIM + kk, &Bs[w * 32 + ii * 8][0]);
            }
            __syncthreads();
            #pragma unroll
            for (int kc = 0; kc < 2; ++kc) {
                bf16x8 af[4], bfr[4];
                #pragma unroll
                for (int mi = 0; mi < 4; ++mi)
                    af[mi] = *(const bf16x8*)((const char*)As + (wy * 64 + mi * 16 + l15) * 128 + (((kc * 4 + quad) ^ sw) << 4));
                #pragma unroll
                for (int nj = 0; nj < 4; ++nj)
                    bfr[nj] = *(const bf16x8*)((const char*)Bs + (wx * 64 + nj * 16 + l15) * 128 + (((kc * 4 + quad) ^ sw) << 4));
                #pragma unroll
                for (int mi = 0; mi < 4; ++mi)
                    #pragma unroll
                    for (int nj = 0; nj < 4; ++nj)
                        s_acc[mi][nj] = __builtin_amdgcn_mfma_f32_16x16x32_bf16(af[mi], bfr[nj], s_acc[mi][nj], 0, 0, 0);
            }
            __syncthreads();
        }

        if (j == qt) {
            #pragma unroll
            for (int mi = 0; mi < 4; ++mi) {
                const int rowb = wy * 64 + mi * 16 + quad * 4;
                #pragma unroll
                for (int nj = 0; nj < 4; ++nj) {
                    const int col = wx * 64 + nj * 16 + l15;
                    #pragma unroll
                    for (int rr = 0; rr < 4; ++rr)
                        if (col >= rowb + rr) s_acc[mi][nj][rr] = 0.f;
                }
            }
        }

        #pragma unroll
        for (int mi = 0; mi < 4; ++mi) {
            const int rowb = wy * 64 + mi * 16 + quad * 4;
            #pragma unroll
            for (int nj = 0; nj < 4; ++nj) {
                const int col = wx * 64 + nj * 16 + l15;
                #pragma unroll
                for (int rr = 0; rr < 4; ++rr)
                    Ps[rowb + rr][col] = f32_to_bf16(s_acc[mi][nj][rr]);
            }
        }
        __syncthreads();

        const u16* vjb = Vb + j * 128;
        #pragma unroll
        for (int kc = 0; kc < 4; ++kc) {
            bf16x8 pf[4];
            #pragma unroll
            for (int mi = 0; mi < 4; ++mi)
                pf[mi] = *(const bf16x8*)(&Ps[wy * 64 + mi * 16 + l15][kc * 32 + quad * 8]);
            #pragma unroll
            for (int nj = 0; nj < 4; ++nj) {
                const bf16x8 vv = *(const bf16x8*)(vjb + (size_t)(nj * 16) * T_DIM + kc * 32);
                #pragma unroll
                for (int mi = 0; mi < 4; ++mi)
                    o_acc[mi][nj] = __builtin_amdgcn_mfma_f32_16x16x32_bf16(pf[mi], vv, o_acc[mi][nj], 0, 0, 0);
            }
        }
    }

    if (hasj0) {
        float* ob = Out + ((size_t)cur_bh * T_DIM + (size_t)cur_qt * 128) * D_DIM;
        #pragma unroll
        for (int mi = 0; mi < 4; ++mi)
            #pragma unroll
            for (int nj = 0; nj < 4; ++nj)
                #pragma unroll
                for (int rr = 0; rr < 4; ++rr)
                    ob[(size_t)(wy * 64 + mi * 16 + quad * 4 + rr) * D_DIM + wx * 64 + nj * 16 + l15] = o_acc[mi][nj][rr];
    } else {
        u16* pb = Part + (size_t)b * 16384;
        #pragma unroll
        for (int mi = 0; mi < 4; ++mi)
            #pragma unroll
            for (int nj = 0; nj < 4; ++nj)
                #pragma unroll
                for (int rr = 0; rr < 4; ++rr)
                    pb[(wy * 64 + mi * 16 + quad * 4 + rr) * 128 + wx * 64 + nj * 16 + l15] = f32_to_bf16(o_acc[mi][nj][rr]);
    }
}

__global__ void combine_kernel(float* __restrict__ Out, const u16* __restrict__ Part) {
    const int bh = blockIdx.x & 15;
    const int qt = 1 + (blockIdx.x >> 4);
    const int ts = bh * 136 + (qt * (qt + 1)) / 2;
    const int lo = ts + 1, hi = ts + qt;
    int bmin = (lo <= 640) ? (lo + 4) / 5 : 128 + (lo - 640 + 3) / 4;
    int writers[4], nw = 0;
    for (int bb = bmin; bb < 512 && run_start(bb) <= hi && nw < 4; ++bb)
        writers[nw++] = bb;
    if (nw == 0) return;
    float* ob = Out + ((size_t)bh * T_DIM + (size_t)qt * 128) * D_DIM;
    const int tid = threadIdx.x;
    #pragma unroll 1
    for (int e = 0; e < 64; ++e) {
        const int idx = e * 256 + tid;
        float a = ob[idx];
        for (int k = 0; k < nw; ++k)
            a += bf16_to_f32(Part[(size_t)writers[k] * 16384 + idx]);
        ob[idx] = a;
    }
}

extern "C" void kernel_launch(void* const* d_in, const int* in_sizes, int n_in,
                              void* d_out, int out_size, void* d_ws, size_t ws_size,
                              hipStream_t stream) {
    const float* Q = (const float*)d_in[0];
    const float* V = (const float*)d_in[2];   // d_in[1] is K == Q, unused
    float* Out = (float*)d_out;

    const size_t QR_E = (size_t)16 * T_DIM * N_DIM;   // 33,554,432 u16
    const size_t VT_E = (size_t)16 * D_DIM * T_DIM;   //  4,194,304 u16
    const size_t UP_E = (size_t)256 * 128 * N_DIM;    // 33,554,432 u16
    const size_t need = (QR_E * 2 + VT_E + UP_E) * 2; // 209,715,200 B

    if (ws_size >= need) {
        // ws: QR | QRt | Vt | UP (exclusive-prefix state, bf16)
        u16* QRw  = (u16*)d_ws;
        u16* QRtw = QRw + QR_E;
        u16* Vtw  = QRtw + QR_E;
        u16* UPw  = Vtw + VT_E;

        ropet_kernel<<<dim3(4096), dim3(256), 0, stream>>>(Q, QRw, QRtw);
        vt_kernel<<<dim3(1024), dim3(256), 0, stream>>>(V, Vtw);
        statescan_kernel<<<dim3(256), dim3(512), 0, stream>>>(QRtw, Vtw, UPw);
        attn3_kernel<<<dim3(256), dim3(512), 0, stream>>>(QRw, UPw, Vtw, Out);
    } else {
        // legacy path: QR | Vt | Part(bf16)
        u16* QRw  = (u16*)d_ws;
        u16* Vtw  = QRw + QR_E;
        u16* Part = Vtw + VT_E;

        rope_kernel<<<dim3(16384), dim3(256), 0, stream>>>(Q, QRw);
        vt_kernel<<<dim3(1024), dim3(256), 0, stream>>>(V, Vtw);
        attn_kernel<<<dim3(512), dim3(256), 0, stream>>>(QRw, Vtw, Out, Part);
        combine_kernel<<<dim3(240), dim3(256), 0, stream>>>(Out, Part);
    }
}

// Round 5
// 360.453 us; speedup vs baseline: 1.4627x; 1.0067x over previous
//
#include <hip/hip_runtime.h>

typedef __bf16 bf16_t;
typedef bf16_t bf16x8 __attribute__((ext_vector_type(8)));
typedef float f32x4 __attribute__((ext_vector_type(4)));
typedef unsigned short u16;
typedef unsigned int u32;

#define T_DIM 2048
#define N_DIM 1024
#define D_DIM 128

__device__ __forceinline__ u16 f32_to_bf16(float f) {
    u32 u = __builtin_bit_cast(u32, f);
    u += 0x7FFFu + ((u >> 16) & 1u);   // RNE
    return (u16)(u >> 16);
}
__device__ __forceinline__ float bf16_to_f32(u16 v) {
    u32 u = (u32)v << 16;
    return __builtin_bit_cast(float, u);
}

typedef __attribute__((address_space(1))) const u32 guint;
typedef __attribute__((address_space(3))) u32 luint;
// async global->LDS, 16B per lane, LDS dst = wave-uniform base + lane*16
__device__ __forceinline__ void stage16(const void* g, void* l) {
    __builtin_amdgcn_global_load_lds((guint*)g, (luint*)l, 16, 0, 0);
}
__device__ __forceinline__ void wait_vm0_barrier() {
    asm volatile("s_waitcnt vmcnt(0)" ::: "memory");
    __builtin_amdgcn_s_barrier();
}

// ---- Kernel 1: fused RoPE + bf16 cast -> QR (t,n) AND QRt (n,t), v3. ----
// 128t x 128n tiles, 2048 blocks: QRt rows get 256B contiguous writes.
__global__ void ropet_kernel(const float* __restrict__ Q, u16* __restrict__ QR,
                             u16* __restrict__ QRt) {
    __shared__ __align__(16) u16 til[128][136];
    const int bh  = blockIdx.x >> 7;
    const int rem = blockIdx.x & 127;
    const int t0 = (rem >> 3) * 128, n0 = (rem & 7) * 128;
    const float* src = Q + (size_t)bh * ((size_t)T_DIM * N_DIM) + (size_t)t0 * N_DIM + n0;
    u16* qdst = QR + (size_t)bh * ((size_t)T_DIM * N_DIM) + (size_t)t0 * N_DIM + n0;
    #pragma unroll
    for (int k = 0; k < 8; ++k) {
        const int slot = k * 256 + threadIdx.x;
        const int r  = slot >> 4;           // 0..127
        const int f8 = slot & 15;           // col octet: cols f8*8..f8*8+7
        const float4 qa = *(const float4*)(src + (size_t)r * N_DIM + f8 * 8);
        const float4 qb = *(const float4*)(src + (size_t)r * N_DIM + f8 * 8 + 4);
        const float vin[4][2] = {{qa.x, qa.y}, {qa.z, qa.w}, {qb.x, qb.y}, {qb.z, qb.w}};
        const int t = t0 + r;
        u16 ov[8];
        #pragma unroll
        for (int pp = 0; pp < 4; ++pp) {
            const int pidx = (n0 >> 1) + f8 * 4 + pp;   // pair index in [0,512)
            const float freq = exp2f((float)pidx * (-1.0f / 32.0f)) * 0.15915494309189535f;
            float ph = (float)t * freq;
            ph -= floorf(ph);
            const float s = __builtin_amdgcn_sinf(ph);
            const float c = __builtin_amdgcn_cosf(ph);
            ov[2 * pp]     = f32_to_bf16(vin[pp][0] * c - vin[pp][1] * s);
            ov[2 * pp + 1] = f32_to_bf16(vin[pp][1] * c + vin[pp][0] * s);
        }
        *(uint4*)(qdst + (size_t)r * N_DIM + f8 * 8) = *(const uint4*)ov;
        *(uint4*)(&til[r][(f8 * 8) ^ (((r >> 3) & 15) << 3)]) = *(const uint4*)ov;
    }
    __syncthreads();
    u16* tdst = QRt + (size_t)bh * ((size_t)N_DIM * T_DIM) + (size_t)n0 * T_DIM + t0;
    #pragma unroll
    for (int k = 0; k < 8; ++k) {
        const int slot = k * 256 + threadIdx.x;
        const int nl = slot >> 4;           // 0..127
        const int to = slot & 15;           // t octet 0..15
        u16 ov2[8];
        #pragma unroll
        for (int e = 0; e < 8; ++e)
            ov2[e] = til[to * 8 + e][nl ^ (to << 3)];
        *(uint4*)(tdst + (size_t)nl * T_DIM + to * 8) = *(const uint4*)ov2;
    }
}

// ---- Kernel 2: V -> bf16, transposed to Vt[bh][d][t] ----
__global__ void vt_kernel(const float* __restrict__ V, u16* __restrict__ Vt) {
    __shared__ u16 tile[64][65];
    const int bh   = blockIdx.x >> 6;
    const int rem  = blockIdx.x & 63;
    const int t0 = (rem >> 1) * 64, d0 = (rem & 1) * 64;
    const float* src = V + ((size_t)bh * T_DIM + t0) * D_DIM + d0;
    #pragma unroll
    for (int k = 0; k < 16; ++k) {
        int linear = k * 256 + threadIdx.x;
        int r = linear >> 6, c = linear & 63;
        tile[r][c] = f32_to_bf16(src[(size_t)r * D_DIM + c]);
    }
    __syncthreads();
    u16* dst = Vt + ((size_t)bh * D_DIM + d0) * T_DIM + t0;
    #pragma unroll
    for (int k = 0; k < 16; ++k) {
        int linear = k * 256 + threadIdx.x;
        int dr = linear >> 6, tc = linear & 63;
        dst[(size_t)dr * T_DIM + tc] = tile[tc][dr];
    }
}

// ---- Kernel 3: fused state+scan, 512 threads, 3-buffer counted-vmcnt pipeline. ----
// One block per (bh, n-tile 128, d-tile 64). Uniform 3 stage16/thread/stage.
__global__ __launch_bounds__(512, 1)
void statescan_kernel(const u16* __restrict__ QRt, const u16* __restrict__ Vt,
                      u16* __restrict__ UP) {
    // A[stg]: 64x64 @ Smem + stg*4096 ; B[stg]: 128x64 @ Smem + 12288 + stg*8192 (u16 units)
    __shared__ __align__(16) u16 Smem[36864];   // 72 KB

    const int b  = blockIdx.x;          // 16 bh * 8 nt * 2 dt
    const int bh = b >> 4;
    const int nt = (b >> 1) & 7;
    const int dt = b & 1;

    const int tid  = threadIdx.x;
    const int w    = tid >> 6;           // 0..7
    const int wy   = w >> 1, wx = w & 1; // wy 0..3
    const int lane = tid & 63;
    const int quad = lane >> 4;
    const int l15  = lane & 15;
    const int sw   = l15 & 7;
    const int srow = lane >> 3;
    const int scol = (lane & 7) ^ (srow & 7);

    const u16* Ag = Vt  + (size_t)bh * ((size_t)D_DIM * T_DIM) + (size_t)(dt * 64)  * T_DIM;
    const u16* Bg = QRt + (size_t)bh * ((size_t)N_DIM * T_DIM) + (size_t)(nt * 128) * T_DIM;

    const f32x4 fz = {0.f, 0.f, 0.f, 0.f};
    f32x4 acc[4];
    #pragma unroll
    for (int nj = 0; nj < 4; ++nj) acc[nj] = fz;

    // uniform: 1 A-load + 2 B-loads per thread per stage
    auto STAGE = [&](int stg, int s) {
        const int toff = s * 64;                     // 64 t per step, 2 steps/chunk
        stage16(Ag + (size_t)(w * 8 + srow) * T_DIM + toff + scol * 8,
                Smem + stg * 4096 + (w * 8) * 64);
        #pragma unroll
        for (int ib = 0; ib < 2; ++ib)
            stage16(Bg + (size_t)(w * 16 + ib * 8 + srow) * T_DIM + toff + scol * 8,
                    Smem + 12288 + stg * 8192 + (w * 16 + ib * 8) * 64);
    };

    u16* upb = UP + (size_t)(bh * 16) * (128 * (size_t)N_DIM)
                  + (size_t)(dt * 64) * N_DIM + nt * 128;

    auto WRITE_UP = [&](int ci) {
        u16* ub = upb + (size_t)ci * (128 * (size_t)N_DIM);
        #pragma unroll
        for (int nj = 0; nj < 4; ++nj)
            #pragma unroll
            for (int rr = 0; rr < 4; ++rr)
                ub[(size_t)(wy * 16 + quad * 4 + rr) * N_DIM + wx * 64 + nj * 16 + l15]
                    = f32_to_bf16(acc[nj][rr]);
    };

    auto MFMA_STEP = [&](int stg) {
        const char* As = (const char*)(Smem + stg * 4096);
        const char* Bs = (const char*)(Smem + 12288 + stg * 8192);
        #pragma unroll
        for (int kc = 0; kc < 2; ++kc) {
            bf16x8 af, bfr[4];
            af = *(const bf16x8*)(As + (wy * 16 + l15) * 128 + (((kc * 4 + quad) ^ sw) << 4));
            #pragma unroll
            for (int nj = 0; nj < 4; ++nj)
                bfr[nj] = *(const bf16x8*)(Bs + (wx * 64 + nj * 16 + l15) * 128 + (((kc * 4 + quad) ^ sw) << 4));
            #pragma unroll
            for (int nj = 0; nj < 4; ++nj)
                acc[nj] = __builtin_amdgcn_mfma_f32_16x16x32_bf16(af, bfr[nj], acc[nj], 0, 0, 0);
        }
    };

    STAGE(0, 0);
    STAGE(1, 1);
    int s0 = 0, s1 = 1, s2 = 2;
    // steps 0..29 accumulate chunks 0..14 (chunk 15's sum is never needed)
    for (int s = 0; s < 29; ++s) {
        asm volatile("s_waitcnt vmcnt(3)" ::: "memory");   // stage s complete (own 3 loads)
        __builtin_amdgcn_s_barrier();                      // ... globally
        if ((s & 1) == 0) WRITE_UP(s >> 1);                // exclusive prefix (stores older than prefetch)
        if (s < 28) STAGE(s2, s + 2);
        MFMA_STEP(s0);
        const int t = s0; s0 = s1; s1 = s2; s2 = t;
    }
    asm volatile("s_waitcnt vmcnt(0)" ::: "memory");
    __builtin_amdgcn_s_barrier();
    MFMA_STEP(s0);
    WRITE_UP(15);
}

// ---- Kernel 4: fused chunk kernel, 512 threads, 3-buffer counted-vmcnt pipeline. ----
// Main (QR_i @ P_i^T, K=1024) and intra (QR_i @ QR_i^T) share the As tile.
__global__ __launch_bounds__(512, 1)
void attn3_kernel(const u16* __restrict__ QR, const u16* __restrict__ UP,
                  const u16* __restrict__ Vt, float* __restrict__ Out) {
    // A[stg]: 128x64 @ Smem + stg*8192 ; B[stg]: 128x64 @ Smem + 24576 + stg*8192 (u16 units)
    __shared__ __align__(16) u16 Smem[49152];   // 96 KB
    u16 (*Ps)[140] = (u16 (*)[140])Smem;        // aliased; used only after the K-loop

    // bijective XCD swizzle (nwg=256, 256%8==0): group blocks sharing bh per XCD
    const int b  = (blockIdx.x & 7) * 32 + (blockIdx.x >> 3);   // 0..255
    const int bh = b >> 4;
    const int i  = b & 15;

    const int tid  = threadIdx.x;
    const int w    = tid >> 6;           // 0..7
    const int wy   = w >> 1, wx = w & 1; // wy 0..3
    const int lane = tid & 63;
    const int quad = lane >> 4;
    const int l15  = lane & 15;
    const int sw   = l15 & 7;
    const int srow = lane >> 3;
    const int scol = (lane & 7) ^ (srow & 7);

    const u16* Ap = QR + (size_t)bh * ((size_t)T_DIM * N_DIM)
                       + (size_t)(i * 128 + w * 16 + srow) * N_DIM + scol * 8;
    const u16* Bp = UP + (size_t)(b * 128 + w * 16 + srow) * N_DIM + scol * 8;

    const f32x4 fz = {0.f, 0.f, 0.f, 0.f};
    f32x4 sm[2][4], si[2][4];
    #pragma unroll
    for (int mi = 0; mi < 2; ++mi)
        #pragma unroll
        for (int nj = 0; nj < 4; ++nj) {
            sm[mi][nj] = fz;
            si[mi][nj] = fz;
        }

    // uniform: 2 A-loads + 2 B-loads per thread per stage
    auto STAGE = [&](int stg, int kk16) {
        const int kk = kk16 * 64;
        #pragma unroll
        for (int ii = 0; ii < 2; ++ii) {
            stage16(Ap + (size_t)(ii * 8) * N_DIM + kk, Smem + stg * 8192 + (w * 16 + ii * 8) * 64);
            stage16(Bp + (size_t)(ii * 8) * N_DIM + kk, Smem + 24576 + stg * 8192 + (w * 16 + ii * 8) * 64);
        }
    };

    auto MFMA_STEP = [&](int stg) {
        const char* As = (const char*)(Smem + stg * 8192);
        const char* Bs = (const char*)(Smem + 24576 + stg * 8192);
        #pragma unroll
        for (int kc = 0; kc < 2; ++kc) {
            bf16x8 af[2], bm[4], bi[4];
            #pragma unroll
            for (int mi = 0; mi < 2; ++mi)
                af[mi] = *(const bf16x8*)(As + (wy * 32 + mi * 16 + l15) * 128 + (((kc * 4 + quad) ^ sw) << 4));
            #pragma unroll
            for (int nj = 0; nj < 4; ++nj) {
                bm[nj] = *(const bf16x8*)(Bs + (wx * 64 + nj * 16 + l15) * 128 + (((kc * 4 + quad) ^ sw) << 4));
                bi[nj] = *(const bf16x8*)(As + (wx * 64 + nj * 16 + l15) * 128 + (((kc * 4 + quad) ^ sw) << 4));
            }
            #pragma unroll
            for (int mi = 0; mi < 2; ++mi)
                #pragma unroll
                for (int nj = 0; nj < 4; ++nj) {
                    sm[mi][nj] = __builtin_amdgcn_mfma_f32_16x16x32_bf16(af[mi], bm[nj], sm[mi][nj], 0, 0, 0);
                    si[mi][nj] = __builtin_amdgcn_mfma_f32_16x16x32_bf16(af[mi], bi[nj], si[mi][nj], 0, 0, 0);
                }
        }
    };

    STAGE(0, 0);
    STAGE(1, 1);
    int s0 = 0, s1 = 1, s2 = 2;
    for (int k = 0; k < 15; ++k) {
        asm volatile("s_waitcnt vmcnt(4)" ::: "memory");   // stage k complete (own 4 loads)
        __builtin_amdgcn_s_barrier();                      // ... globally
        if (k < 14) STAGE(s2, k + 2);
        MFMA_STEP(s0);
        const int t = s0; s0 = s1; s1 = s2; s2 = t;
    }
    asm volatile("s_waitcnt vmcnt(0)" ::: "memory");
    __builtin_amdgcn_s_barrier();
    MFMA_STEP(s0);

    // strict causal on the diagonal tile: keep col < row
    #pragma unroll
    for (int mi = 0; mi < 2; ++mi) {
        const int rowb = wy * 32 + mi * 16 + quad * 4;
        #pragma unroll
        for (int nj = 0; nj < 4; ++nj) {
            const int col = wx * 64 + nj * 16 + l15;
            #pragma unroll
            for (int rr = 0; rr < 4; ++rr)
                if (col >= rowb + rr) si[mi][nj][rr] = 0.f;
        }
    }
    __syncthreads();   // all MFMA LDS reads done before Ps overwrites buffers
    // C/D -> A-operand layout via LDS (cross-wave in wx => barrier both sides)
    #pragma unroll
    for (int mi = 0; mi < 2; ++mi) {
        const int rowb = wy * 32 + mi * 16 + quad * 4;
        #pragma unroll
        for (int nj = 0; nj < 4; ++nj) {
            const int col = wx * 64 + nj * 16 + l15;
            #pragma unroll
            for (int rr = 0; rr < 4; ++rr)
                Ps[rowb + rr][col] = f32_to_bf16(si[mi][nj][rr]);
        }
    }
    __syncthreads();

    const u16* vjb = Vt + (size_t)bh * ((size_t)D_DIM * T_DIM)
                        + (size_t)(wx * 64 + l15) * T_DIM + i * 128 + quad * 8;
    #pragma unroll
    for (int kc = 0; kc < 4; ++kc) {
        bf16x8 pf[2];
        #pragma unroll
        for (int mi = 0; mi < 2; ++mi)
            pf[mi] = *(const bf16x8*)(&Ps[wy * 32 + mi * 16 + l15][kc * 32 + quad * 8]);
        #pragma unroll
        for (int nj = 0; nj < 4; ++nj) {
            const bf16x8 vv = *(const bf16x8*)(vjb + (size_t)(nj * 16) * T_DIM + kc * 32);
            #pragma unroll
            for (int mi = 0; mi < 2; ++mi)
                sm[mi][nj] = __builtin_amdgcn_mfma_f32_16x16x32_bf16(pf[mi], vv, sm[mi][nj], 0, 0, 0);
        }
    }

    float* ob = Out + ((size_t)bh * T_DIM + (size_t)i * 128) * D_DIM;
    #pragma unroll
    for (int mi = 0; mi < 2; ++mi)
        #pragma unroll
        for (int nj = 0; nj < 4; ++nj)
            #pragma unroll
            for (int rr = 0; rr < 4; ++rr)
                ob[(size_t)(wy * 32 + mi * 16 + quad * 4 + rr) * D_DIM + wx * 64 + nj * 16 + l15]
                    = sm[mi][nj][rr];
}

// ======================= legacy fallback path (ws too small) =======================
__global__ void rope_kernel(const float* __restrict__ Q, u16* __restrict__ QR) {
    const int g = blockIdx.x * 256 + threadIdx.x;
    const int base = g * 4;
    const int t  = (base >> 9) & (T_DIM - 1);
    const int p0 = base & 511;
    const float4 qa = ((const float4*)Q)[g * 2];
    const float4 qb = ((const float4*)Q)[g * 2 + 1];
    const float vin[4][2] = {{qa.x, qa.y}, {qa.z, qa.w}, {qb.x, qb.y}, {qb.z, qb.w}};
    u16 ov[8];
    #pragma unroll
    for (int uu = 0; uu < 4; ++uu) {
        const float freq = exp2f((float)(p0 + uu) * (-1.0f / 32.0f)) * 0.15915494309189535f;
        float ph = (float)t * freq;
        ph = ph - floorf(ph);
        const float s = __builtin_amdgcn_sinf(ph);
        const float c = __builtin_amdgcn_cosf(ph);
        ov[2 * uu]     = f32_to_bf16(vin[uu][0] * c - vin[uu][1] * s);
        ov[2 * uu + 1] = f32_to_bf16(vin[uu][1] * c + vin[uu][0] * s);
    }
    ((uint4*)QR)[g] = *(const uint4*)ov;
}

__device__ __forceinline__ int run_start(int b) { return b < 128 ? 5 * b : 640 + 4 * (b - 128); }

__global__ __launch_bounds__(256, 2)
void attn_kernel(const u16* __restrict__ QR, const u16* __restrict__ Vt,
                 float* __restrict__ Out, u16* __restrict__ Part) {
    __shared__ __align__(16) u16 Smem[17920];
    u16 (*As)[64]  = (u16 (*)[64])Smem;
    u16 (*Bs)[64]  = (u16 (*)[64])(Smem + 8192);
    u16 (*Ps)[140] = (u16 (*)[140])Smem;

    const int b     = blockIdx.x;
    const int start = run_start(b);
    const int len   = b < 128 ? 5 : 4;

    const int tid  = threadIdx.x;
    const int w    = tid >> 6;
    const int wy   = w >> 1, wx = w & 1;
    const int lane = tid & 63;
    const int quad = lane >> 4;
    const int l15  = lane & 15;
    const int sw   = l15 & 7;
    const int srow = lane >> 3;
    const int scol = (lane & 7) ^ (srow & 7);

    const f32x4 fz = {0.f, 0.f, 0.f, 0.f};
    f32x4 o_acc[4][4];
    int cur_bh = -1, cur_qt = -1;
    bool hasj0 = false;
    const u16* QRb = QR;
    const u16* Ap  = QR;
    const u16* Vb  = Vt;

    for (int it = 0; it < len; ++it) {
        const int i = start + it;
        const int bh = i / 136;
        const int r  = i - bh * 136;
        int qt = 15, j = 0, acc = 0;
        #pragma unroll 1
        for (int q = 0; q < 16; ++q) {
            if (r < acc + q + 1) { qt = q; j = r - acc; break; }
            acc += q + 1;
        }

        if (qt != cur_qt || bh != cur_bh) {
            if (cur_qt >= 0) {
                if (hasj0) {
                    float* ob = Out + ((size_t)cur_bh * T_DIM + (size_t)cur_qt * 128) * D_DIM;
                    #pragma unroll
                    for (int mi = 0; mi < 4; ++mi)
                        #pragma unroll
                        for (int nj = 0; nj < 4; ++nj)
                            #pragma unroll
                            for (int rr = 0; rr < 4; ++rr)
                                ob[(size_t)(wy * 64 + mi * 16 + quad * 4 + rr) * D_DIM + wx * 64 + nj * 16 + l15] = o_acc[mi][nj][rr];
                } else {
                    u16* pb = Part + (size_t)b * 16384;
                    #pragma unroll
                    for (int mi = 0; mi < 4; ++mi)
                        #pragma unroll
                        for (int nj = 0; nj < 4; ++nj)
                            #pragma unroll
                            for (int rr = 0; rr < 4; ++rr)
                                pb[(wy * 64 + mi * 16 + quad * 4 + rr) * 128 + wx * 64 + nj * 16 + l15] = f32_to_bf16(o_acc[mi][nj][rr]);
                }
            }
            cur_bh = bh; cur_qt = qt; hasj0 = (j == 0);
            #pragma unroll
            for (int mi = 0; mi < 4; ++mi)
                #pragma unroll
                for (int nj = 0; nj < 4; ++nj)
                    o_acc[mi][nj] = fz;
            QRb = QR + (size_t)bh * (T_DIM * N_DIM);
            Ap  = QRb + (size_t)(qt * 128 + w * 32 + srow) * N_DIM + scol * 8;
            Vb  = Vt + (size_t)bh * (D_DIM * T_DIM) + (size_t)(wx * 64 + l15) * T_DIM + quad * 8;
        }

        const u16* Bp = QRb + (size_t)(j * 128 + w * 32 + srow) * N_DIM + scol * 8;
        f32x4 s_acc[4][4];
        #pragma unroll
        for (int mi = 0; mi < 4; ++mi)
            #pragma unroll
            for (int nj = 0; nj < 4; ++nj)
                s_acc[mi][nj] = fz;

        __syncthreads();

        for (int kk = 0; kk < N_DIM; kk += 64) {
            #pragma unroll
            for (int ii = 0; ii < 4; ++ii) {
                stage16(Ap + (size_t)ii * 8 * N_DIM + kk, &As[w * 32 + ii * 8][0]);
                stage16(Bp + (size_t)ii * 8 * N_DIM + kk, &Bs[w * 32 + ii * 8][0]);
            }
            __syncthreads();
            #pragma unroll
            for (int kc = 0; kc < 2; ++kc) {
                bf16x8 af[4], bfr[4];
                #pragma unroll
                for (int mi = 0; mi < 4; ++mi)
                    af[mi] = *(const bf16x8*)((const char*)As + (wy * 64 + mi * 16 + l15) * 128 + (((kc * 4 + quad) ^ sw) << 4));
                #pragma unroll
                for (int nj = 0; nj < 4; ++nj)
                    bfr[nj] = *(const bf16x8*)((const char*)Bs + (wx * 64 + nj * 16 + l15) * 128 + (((kc * 4 + quad) ^ sw) << 4));
                #pragma unroll
                for (int mi = 0; mi < 4; ++mi)
                    #pragma unroll
                    for (int nj = 0; nj < 4; ++nj)
                        s_acc[mi][nj] = __builtin_amdgcn_mfma_f32_16x16x32_bf16(af[mi], bfr[nj], s_acc[mi][nj], 0, 0, 0);
            }
            __syncthreads();
        }

        if (j == qt) {
            #pragma unroll
            for (int mi = 0; mi < 4; ++mi) {
                const int rowb = wy * 64 + mi * 16 + quad * 4;
                #pragma unroll
                for (int nj = 0; nj < 4; ++nj) {
                    const int col = wx * 64 + nj * 16 + l15;
                    #pragma unroll
                    for (int rr = 0; rr < 4; ++rr)
                        if (col >= rowb + rr) s_acc[mi][nj][rr] = 0.f;
                }
            }
        }

        #pragma unroll
        for (int mi = 0; mi < 4; ++mi) {
            const int rowb = wy * 64 + mi * 16 + quad * 4;
            #pragma unroll
            for (int nj = 0; nj < 4; ++nj) {
                const int col = wx * 64 + nj * 16 + l15;
                #pragma unroll
                for (int rr = 0; rr < 4; ++rr)
                    Ps[rowb + rr][col] = f32_to_bf16(s_acc[mi][nj][rr]);
            }
        }
        __syncthreads();

        const u16* vjb = Vb + j * 128;
        #pragma unroll
        for (int kc = 0; kc < 4; ++kc) {
            bf16x8 pf[4];
            #pragma unroll
            for (int mi = 0; mi < 4; ++mi)
                pf[mi] = *(const bf16x8*)(&Ps[wy * 64 + mi * 16 + l15][kc * 32 + quad * 8]);
            #pragma unroll
            for (int nj = 0; nj < 4; ++nj) {
                const bf16x8 vv = *(const bf16x8*)(vjb + (size_t)(nj * 16) * T_DIM + kc * 32);
                #pragma unroll
                for (int mi = 0; mi < 4; ++mi)
                    o_acc[mi][nj] = __builtin_amdgcn_mfma_f32_16x16x32_bf16(pf[mi], vv, o_acc[mi][nj], 0, 0, 0);
            }
        }
    }

    if (hasj0) {
        float* ob = Out + ((size_t)cur_bh * T_DIM + (size_t)cur_qt * 128) * D_DIM;
        #pragma unroll
        for (int mi = 0; mi < 4; ++mi)
            #pragma unroll
            for (int nj = 0; nj < 4; ++nj)
                #pragma unroll
                for (int rr = 0; rr < 4; ++rr)
                    ob[(size_t)(wy * 64 + mi * 16 + quad * 4 + rr) * D_DIM + wx * 64 + nj * 16 + l15] = o_acc[mi][nj][rr];
    } else {
        u16* pb = Part + (size_t)b * 16384;
        #pragma unroll
        for (int mi = 0; mi < 4; ++mi)
            #pragma unroll
            for (int nj = 0; nj < 4; ++nj)
                #pragma unroll
                for (int rr = 0; rr < 4; ++rr)
                    pb[(wy * 64 + mi * 16 + quad * 4 + rr) * 128 + wx * 64 + nj * 16 + l15] = f32_to_bf16(o_acc[mi][nj][rr]);
    }
}

__global__ void combine_kernel(float* __restrict__ Out, const u16* __restrict__ Part) {
    const int bh = blockIdx.x & 15;
    const int qt = 1 + (blockIdx.x >> 4);
    const int ts = bh * 136 + (qt * (qt + 1)) / 2;
    const int lo = ts + 1, hi = ts + qt;
    int bmin = (lo <= 640) ? (lo + 4) / 5 : 128 + (lo - 640 + 3) / 4;
    int writers[4], nw = 0;
    for (int bb = bmin; bb < 512 && run_start(bb) <= hi && nw < 4; ++bb)
        writers[nw++] = bb;
    if (nw == 0) return;
    float* ob = Out + ((size_t)bh * T_DIM + (size_t)qt * 128) * D_DIM;
    const int tid = threadIdx.x;
    #pragma unroll 1
    for (int e = 0; e < 64; ++e) {
        const int idx = e * 256 + tid;
        float a = ob[idx];
        for (int k = 0; k < nw; ++k)
            a += bf16_to_f32(Part[(size_t)writers[k] * 16384 + idx]);
        ob[idx] = a;
    }
}

extern "C" void kernel_launch(void* const* d_in, const int* in_sizes, int n_in,
                              void* d_out, int out_size, void* d_ws, size_t ws_size,
                              hipStream_t stream) {
    const float* Q = (const float*)d_in[0];
    const float* V = (const float*)d_in[2];   // d_in[1] is K == Q, unused
    float* Out = (float*)d_out;

    const size_t QR_E = (size_t)16 * T_DIM * N_DIM;   // 33,554,432 u16
    const size_t VT_E = (size_t)16 * D_DIM * T_DIM;   //  4,194,304 u16
    const size_t UP_E = (size_t)256 * 128 * N_DIM;    // 33,554,432 u16
    const size_t need = (QR_E * 2 + VT_E + UP_E) * 2; // 209,715,200 B

    if (ws_size >= need) {
        // ws: QR | QRt | Vt | UP (exclusive-prefix state, bf16)
        u16* QRw  = (u16*)d_ws;
        u16* QRtw = QRw + QR_E;
        u16* Vtw  = QRtw + QR_E;
        u16* UPw  = Vtw + VT_E;

        ropet_kernel<<<dim3(2048), dim3(256), 0, stream>>>(Q, QRw, QRtw);
        vt_kernel<<<dim3(1024), dim3(256), 0, stream>>>(V, Vtw);
        statescan_kernel<<<dim3(256), dim3(512), 0, stream>>>(QRtw, Vtw, UPw);
        attn3_kernel<<<dim3(256), dim3(512), 0, stream>>>(QRw, UPw, Vtw, Out);
    } else {
        // legacy path: QR | Vt | Part(bf16)
        u16* QRw  = (u16*)d_ws;
        u16* Vtw  = QRw + QR_E;
        u16* Part = Vtw + VT_E;

        rope_kernel<<<dim3(16384), dim3(256), 0, stream>>>(Q, QRw);
        vt_kernel<<<dim3(1024), dim3(256), 0, stream>>>(V, Vtw);
        attn_kernel<<<dim3(512), dim3(256), 0, stream>>>(QRw, Vtw, Out, Part);
        combine_kernel<<<dim3(240), dim3(256), 0, stream>>>(Out, Part);
    }
}